// Round 9
// baseline (1388.818 us; speedup 1.0000x reference)
//
#include <hip/hip_runtime.h>
#include <cstdint>

#define B_ 2
#define S_ 2048
#define D_ 1024
#define H_ 16
#define DH_ 64
#define F_ 4096
#define E_ 8
#define M_ (B_*S_)   // 4096 rows
#define KVB 64

using u16 = unsigned short;
typedef __bf16 bf16x8 __attribute__((ext_vector_type(8)));
typedef float f32x4 __attribute__((ext_vector_type(4)));
typedef u16 u16x8 __attribute__((ext_vector_type(8)));
typedef u16 u16x4 __attribute__((ext_vector_type(4)));
typedef unsigned int u32x2 __attribute__((ext_vector_type(2)));

__device__ __forceinline__ u16 f2bf(float f) {
  union { float f; uint32_t u; } x; x.f = f;
  uint32_t u = x.u;
  u += 0x7fffu + ((u >> 16) & 1u);   // RNE
  return (u16)(u >> 16);
}

#define GLD_LDS16(g, l) __builtin_amdgcn_global_load_lds( \
    (__attribute__((address_space(1))) void*)(g), \
    (__attribute__((address_space(3))) void*)(l), 16, 0, 0)

// ---------------------------------------------------------------- converts
__global__ __launch_bounds__(256) void cvt_kernel(const float* __restrict__ in,
                                                  u16* __restrict__ out) {
  const size_t i = ((size_t)blockIdx.x * 256 + threadIdx.x) * 4;
  float4 v = *(const float4*)(in + i);
  u16x4 o = { f2bf(v.x), f2bf(v.y), f2bf(v.z), f2bf(v.w) };
  *(u16x4*)(out + i) = o;
}

// in: [z][R][C] f32 -> out: z-th block, [C][R] bf16 with leading dim ldo.
__global__ __launch_bounds__(256) void transpose_cvt(const float* __restrict__ in,
                                                     u16* __restrict__ out,
                                                     int R, int C, int ldo,
                                                     long zin, long zout) {
  __shared__ u16 tile[32][33];
  in  += (size_t)blockIdx.z * zin;
  out += (size_t)blockIdx.z * zout;
  const int tx = threadIdx.x, ty = threadIdx.y;
  const int c0 = blockIdx.x * 32, r0 = blockIdx.y * 32;
  #pragma unroll
  for (int rr = ty; rr < 32; rr += 8)
    tile[rr][tx] = f2bf(in[(size_t)(r0 + rr) * C + c0 + tx]);
  __syncthreads();
  #pragma unroll
  for (int rr = ty; rr < 32; rr += 8)
    out[(size_t)(c0 + rr) * ldo + r0 + tx] = tile[tx][rr];
}

enum { EPI_BF16 = 0, EPI_F32 = 1, EPI_GELU = 2, EPI_MOE = 3, EPI_GG = 4, EPI_PART = 5 };

// ---------------------------------------------------------------- GEMM 128^2 (2-phase)
#define BM 128
#define BN 128
#define BK 64

template<int EPI, bool INIT>
__global__ __launch_bounds__(256, 2) void gemm_bf16(
    const u16* __restrict__ A, const u16* __restrict__ Bt, int K,
    const float* __restrict__ bias, void* __restrict__ outp, int ldc,
    const float* __restrict__ gate)
{
  __shared__ u16 ldsA[2][BM * BK];
  __shared__ u16 ldsB[2][BN * BK];
  const int tid = threadIdx.x;
  const int w = tid >> 6, l = tid & 63;
  const int tile_n = blockIdx.x * BN;
  const int tile_m = blockIdx.y * BM;
  const int wr = w >> 1, wc = w & 1;
  const int l15 = l & 15, l4 = l >> 4;

  f32x4 acc[4][4] = {};

  const int srow = (w << 5) + (l >> 3);
  const int schunk = (l & 7) ^ (l >> 3);
  const u16* srcA0 = A + (size_t)(tile_m + srow) * K + schunk * 8;
  const u16* srcB0 = Bt + (size_t)(tile_n + srow) * K + schunk * 8;

  auto stage = [&](int buf, int kt) {
    #pragma unroll
    for (int i = 0; i < 4; ++i) {
      GLD_LDS16(srcA0 + kt + (size_t)(i * 8) * K, &ldsA[buf][((w << 5) + i * 8) * BK]);
      GLD_LDS16(srcB0 + kt + (size_t)(i * 8) * K, &ldsB[buf][((w << 5) + i * 8) * BK]);
    }
  };

  auto compute = [&](int buf) {
    #pragma unroll
    for (int ks = 0; ks < 2; ++ks) {
      bf16x8 af[4], bfr[4];
      #pragma unroll
      for (int m = 0; m < 4; ++m) {
        const int r = wr * 64 + m * 16 + l15;
        const int c = ((ks << 2) + l4) ^ (r & 7);
        af[m] = *(const bf16x8*)&ldsA[buf][r * BK + c * 8];
      }
      #pragma unroll
      for (int n = 0; n < 4; ++n) {
        const int r = wc * 64 + n * 16 + l15;
        const int c = ((ks << 2) + l4) ^ (r & 7);
        bfr[n] = *(const bf16x8*)&ldsB[buf][r * BK + c * 8];
      }
      #pragma unroll
      for (int m = 0; m < 4; ++m)
        #pragma unroll
        for (int n = 0; n < 4; ++n)
          acc[m][n] = __builtin_amdgcn_mfma_f32_16x16x32_bf16(af[m], bfr[n], acc[m][n], 0, 0, 0);
    }
  };

  const int nT = K / BK;
  stage(0, 0);
  __syncthreads();
  int buf = 0;
  for (int t = 0; t < nT; ++t) {
    if (t + 1 < nT) stage(buf ^ 1, (t + 1) * BK);
    compute(buf);
    __syncthreads();
    buf ^= 1;
  }

  #pragma unroll
  for (int m = 0; m < 4; ++m) {
    const int row0 = tile_m + wr * 64 + m * 16 + (l4 << 2);
    #pragma unroll
    for (int n = 0; n < 4; ++n) {
      const int col = tile_n + wc * 64 + n * 16 + l15;
      const float bv = bias[col];
      #pragma unroll
      for (int i = 0; i < 4; ++i) {
        const int row = row0 + i;
        const float v = acc[m][n][i] + bv;
        const size_t idx = (size_t)row * ldc + col;
        if (EPI == EPI_BF16) {
          ((u16*)outp)[idx] = f2bf(v);
        } else if (EPI == EPI_F32) {
          ((float*)outp)[idx] = v;
        } else if (EPI == EPI_GELU) {
          const float e = __expf(-1.5957691216f * (v + 0.044715f * v * v * v));
          ((u16*)outp)[idx] = f2bf(v / (1.0f + e));
        } else if (EPI == EPI_MOE) {
          const float g = gate[(size_t)row * E_];
          float* o = (float*)outp;
          if (INIT) o[idx] = g * v;
          else      o[idx] += g * v;
        }
      }
    }
  }
}

// ---------------------------------------------------------------- GEMM 256^2, r5 8-phase (best measured)
// SWZ=0: bijective XCD chunk swizzle. SWZ=1 (GG only, grid 16x16x8):
// z = hw&7 pins each expert to one XCD; by-inner so concurrent blocks share
// the same B-panel in that XCD's L2.
#define RD_A8(BUF, MH) \
  _Pragma("unroll") for (int mm = 0; mm < 4; ++mm) \
    _Pragma("unroll") for (int ks = 0; ks < 2; ++ks) \
      af[mm][ks] = *(const bf16x8*)&ldsA[(BUF) * 16384 + (MH) * 8192 + \
        (((wr << 6) | (mm * 16 + l15)) << 6) + (((ks * 4 + l4) ^ (l15 & 7)) << 3)];
#define RD_B4(BUF, NH) \
  _Pragma("unroll") for (int nn = 0; nn < 2; ++nn) \
    _Pragma("unroll") for (int ks = 0; ks < 2; ++ks) \
      bfr[NH][nn][ks] = *(const bf16x8*)&ldsB[(BUF) * 16384 + (NH) * 8192 + \
        (((wc << 5) | (nn * 16 + l15)) << 6) + (((ks * 4 + l4) ^ (l15 & 7)) << 3)];
#define STAGE_A(Q, BUF, KT) \
  _Pragma("unroll") for (int j = 0; j < 2; ++j) \
    GLD_LDS16(Ag + (size_t)(tm + rgA[j][Q]) * lda + (KT) + scol, \
              &ldsA[(BUF) * 16384 + (Q) * 8192 + dstoff[j]]);
#define STAGE_B(Q, BUF, KT) \
  _Pragma("unroll") for (int j = 0; j < 2; ++j) \
    GLD_LDS16(Bg + (size_t)(tn + rgB[j][Q]) * ldb + (KT) + scol, \
              &ldsB[(BUF) * 16384 + (Q) * 8192 + dstoff[j]]);
#define MFMA_Q(MH, NH) \
  __builtin_amdgcn_s_setprio(1); \
  _Pragma("unroll") for (int mm = 0; mm < 4; ++mm) \
    _Pragma("unroll") for (int nn = 0; nn < 2; ++nn) \
      _Pragma("unroll") for (int ks = 0; ks < 2; ++ks) \
        acc[(MH)*4+mm][(NH)*2+nn] = __builtin_amdgcn_mfma_f32_16x16x32_bf16( \
            af[mm][ks], bfr[NH][nn][ks], acc[(MH)*4+mm][(NH)*2+nn], 0, 0, 0); \
  __builtin_amdgcn_s_setprio(0);
#define VMC6 asm volatile("s_waitcnt vmcnt(6)" ::: "memory")
#define VMC0 asm volatile("s_waitcnt vmcnt(0)" ::: "memory")
#define SCB  __builtin_amdgcn_sched_barrier(0)
#define BARR __builtin_amdgcn_s_barrier()
#define LGKM0 do { asm volatile("s_waitcnt lgkmcnt(0)" ::: "memory"); SCB; } while (0)

#define PH_TAIL(MH, NH) \
  SCB; BARR; LGKM0; MFMA_Q(MH, NH)

#define TILE_MAIN(BUF, KT1, KT2) \
  RD_A8(BUF, 0) RD_B4(BUF, 0) STAGE_A(1, (BUF) ^ 1, KT1) PH_TAIL(0, 0) BARR; \
  RD_B4(BUF, 1)               STAGE_A(0, BUF, KT2)       PH_TAIL(0, 1) BARR; \
  RD_A8(BUF, 1)               STAGE_B(0, BUF, KT2)       PH_TAIL(1, 0) BARR; \
                              STAGE_B(1, BUF, KT2)       PH_TAIL(1, 1) VMC6; BARR;

#define TILE_PEN(BUF, KT1) \
  RD_A8(BUF, 0) RD_B4(BUF, 0) STAGE_A(1, (BUF) ^ 1, KT1) PH_TAIL(0, 0) BARR; \
  RD_B4(BUF, 1)                                          PH_TAIL(0, 1) BARR; \
  RD_A8(BUF, 1)                                          PH_TAIL(1, 0) BARR; \
                                                         PH_TAIL(1, 1) VMC0; BARR;

#define TILE_LAST(BUF) \
  RD_A8(BUF, 0) RD_B4(BUF, 0) PH_TAIL(0, 0) BARR; \
  RD_B4(BUF, 1)               PH_TAIL(0, 1) BARR; \
  RD_A8(BUF, 1)               PH_TAIL(1, 0) BARR; \
                              PH_TAIL(1, 1)

template<int EPI, int SWZ>
__global__ __launch_bounds__(512, 2) void gemm256(
    const u16* __restrict__ A, const u16* __restrict__ Bt,
    const int K, const int lda, const int ldb,
    const long zA, const long zB, const long zC, const int zBias,
    const float* __restrict__ bias, void* __restrict__ outp, const int ldc,
    const float* __restrict__ gate)
{
  extern __shared__ u16 lds[];
  u16* ldsA = lds;            // [2][2][128][64]
  u16* ldsB = lds + 32768;
  const int tid = threadIdx.x, w = tid >> 6, l = tid & 63;
  const int wr = w >> 2, wc = w & 3;
  const int l15 = l & 15, l4 = l >> 4;

  const unsigned nx = gridDim.x, ny = gridDim.y;
  const unsigned hw = blockIdx.x + nx * (blockIdx.y + ny * blockIdx.z);
  unsigned bx, by; int z;
  if (SWZ == 1) {
    // expert-per-XCD (requires nx=16, ny=16, nz=8); by-inner for B-panel reuse
    z = (int)(hw & 7u);
    const unsigned rest = hw >> 3;
    by = rest & 15u;
    bx = rest >> 4;
  } else {
    const unsigned nwg = nx * ny * gridDim.z;
    unsigned wg = (hw & 7u) * (nwg >> 3) + (hw >> 3);
    bx = wg % nx;
    const unsigned rest = wg / nx;
    by = rest % ny;
    z = (int)(rest / ny);
  }

  const u16* Ag = A + (size_t)z * zA;
  const u16* Bg = Bt + (size_t)z * zB;
  const int tn = bx * 256, tm = by * 256;
  const int scol = ((l & 7) ^ (l >> 3)) * 8;

  f32x4 acc[8][4] = {};
  bf16x8 af[4][2];        // current A half
  bf16x8 bfr[2][2][2];    // both B halves resident

  int rgA[2][2], rgB[2][2], dstoff[2];
  #pragma unroll
  for (int j = 0; j < 2; ++j) {
    const int s = (j * 8 + w) * 8 + (l >> 3);
    dstoff[j] = (j * 8 + w) * 512;
    #pragma unroll
    for (int q = 0; q < 2; ++q) {
      rgA[j][q] = ((s >> 6) << 7) | (q << 6) | (s & 63);
      rgB[j][q] = ((s >> 5) << 6) | (q << 5) | (s & 31);
    }
  }

  // prologue FIFO: tile0 {A0,B0,B1,A1} -> buf0, tile1 {A0,B0,B1} -> buf1
  STAGE_A(0, 0, 0) STAGE_B(0, 0, 0) STAGE_B(1, 0, 0) STAGE_A(1, 0, 0)
  STAGE_A(0, 1, 64) STAGE_B(0, 1, 64) STAGE_B(1, 1, 64)
  VMC6;                       // tile0's 8 loads landed
  __syncthreads();

  const int nT = K / 64;      // even by construction
  for (int t = 0; t < nT - 2; t += 2) {
    TILE_MAIN(0, (t + 1) * 64, (t + 2) * 64)
    TILE_MAIN(1, (t + 2) * 64, (t + 3) * 64)
  }
  TILE_PEN(0, (nT - 1) * 64)  // tile nT-2
  TILE_LAST(1)                // tile nT-1

  // ---------------- epilogue
  if (EPI == EPI_BF16 || EPI == EPI_GG) {
    // coalesced bf16 store via LDS bounce: slab [32][260] f32 per (mh,mm)
    float* sl = (float*)lds;
    const int r2 = tid >> 4, c2 = (tid & 15) * 16;
    #pragma unroll
    for (int mh = 0; mh < 2; ++mh)
    #pragma unroll
    for (int mm = 0; mm < 4; ++mm) {
      BARR;
      #pragma unroll
      for (int nh = 0; nh < 2; ++nh)
      #pragma unroll
      for (int nn = 0; nn < 2; ++nn) {
        const f32x4 a = acc[mh * 4 + mm][nh * 2 + nn];
        const int c = wc * 64 + nh * 32 + nn * 16 + l15;
        #pragma unroll
        for (int i = 0; i < 4; ++i)
          sl[(wr * 16 + (l4 << 2) + i) * 260 + c] = a[i];
      }
      BARR;
      const int grow = tm + ((r2 >> 4) << 7) + mh * 64 + mm * 16 + (r2 & 15);
      float v[16];
      #pragma unroll
      for (int j = 0; j < 4; ++j) {
        const float4 tf = *(const float4*)&sl[r2 * 260 + c2 + j * 4];
        v[j*4+0] = tf.x; v[j*4+1] = tf.y; v[j*4+2] = tf.z; v[j*4+3] = tf.w;
      }
      u16 o[16];
      const float g = (EPI == EPI_GG) ? gate[(size_t)grow * E_ + z] : 0.0f;
      #pragma unroll
      for (int j = 0; j < 16; ++j) {
        float x = v[j] + bias[(EPI == EPI_GG ? z * zBias : 0) + tn + c2 + j];
        if (EPI == EPI_GG) {
          const float e = __expf(-1.5957691216f * (x + 0.044715f * x * x * x));
          x = (x / (1.0f + e)) * g;
        }
        o[j] = f2bf(x);
      }
      u16* dst = (u16*)outp + (size_t)z * zC + (size_t)grow * ldc + tn + c2;
      *(u16x8*)dst = *(const u16x8*)&o[0];
      *(u16x8*)(dst + 8) = *(const u16x8*)&o[8];
    }
  } else {  // EPI_PART: f32 direct
    #pragma unroll
    for (int mh = 0; mh < 2; ++mh)
    #pragma unroll
    for (int mm = 0; mm < 4; ++mm) {
      const int row0 = tm + wr * 128 + mh * 64 + mm * 16 + (l4 << 2);
      #pragma unroll
      for (int nh = 0; nh < 2; ++nh)
      #pragma unroll
      for (int nn = 0; nn < 2; ++nn) {
        const int col = tn + wc * 64 + nh * 32 + nn * 16 + l15;
        const f32x4 a = acc[mh * 4 + mm][nh * 2 + nn];
        #pragma unroll
        for (int i = 0; i < 4; ++i)
          ((float*)outp)[(size_t)z * zC + (size_t)(row0 + i) * ldc + col] = a[i];
      }
    }
  }
}
#undef RD_A8
#undef RD_B4
#undef STAGE_A
#undef STAGE_B
#undef MFMA_Q
#undef PH_TAIL
#undef TILE_MAIN
#undef TILE_PEN
#undef TILE_LAST

// ---------------------------------------------------------------- moe reduce (8 partials)
__global__ __launch_bounds__(256) void moe_reduce(
    const float* __restrict__ part, const float* __restrict__ gate,
    const float* __restrict__ b2, float* __restrict__ moe)
{
  const int row = blockIdx.x;
  const int c = threadIdx.x * 4;
  const size_t o = (size_t)row * D_ + c;
  float4 s = *(const float4*)(part + o);
  #pragma unroll
  for (int zz = 1; zz < 8; ++zz) {
    const float4 p = *(const float4*)(part + (size_t)zz * M_ * D_ + o);
    s.x += p.x; s.y += p.y; s.z += p.z; s.w += p.w;
  }
  #pragma unroll
  for (int e = 0; e < 8; ++e) {
    const float g = gate[(size_t)row * 8 + e];
    const float4 bv = *(const float4*)(b2 + (size_t)e * D_ + c);
    s.x += g * bv.x; s.y += g * bv.y; s.z += g * bv.z; s.w += g * bv.w;
  }
  *(float4*)(moe + o) = s;
}

// ---------------------------------------------------------------- attention
__global__ __launch_bounds__(256, 2) void attn2_kernel(
    const u16* __restrict__ qkv, const float* __restrict__ mask,
    u16* __restrict__ ctx)
{
  __shared__ u16 kbuf[2][KVB * 64];
  __shared__ u16 vbuf[2][KVB * 64];
  __shared__ __align__(16) u16 plds[4][16 * 64];
  __shared__ float smbuf[4][16];

  const int tid = threadIdx.x, w = tid >> 6, l = tid & 63;
  const int l15 = l & 15, l4 = l >> 4;

  // XCD swizzle: nwg = 32*16*2 = 1024
  unsigned wg = blockIdx.x + 32u * (blockIdx.y + 16u * blockIdx.z);
  wg = (wg & 7u) * 128u + (wg >> 3);
  const int qt = (int)(wg & 31u) * 64;
  const unsigned r1 = wg >> 5;
  const int h = (int)(r1 & 15u), b = (int)(r1 >> 4);

  const int qrow = qt + w * 16 + l15;
  const size_t grow = (size_t)b * S_ + qrow;
  bf16x8 qf[2];
  qf[0] = *(const bf16x8*)(qkv + grow * 3072 + h * 64 + l4 * 8);
  qf[1] = *(const bf16x8*)(qkv + grow * 3072 + h * 64 + 32 + l4 * 8);

  const float* maskr = mask + (size_t)b * S_ * S_ + (size_t)qrow * S_;

  f32x4 cacc[4] = {};
  float mrun = -3.0e38f, lrun = 0.0f;

  auto stage = [&](int bf, int kc) {
    #pragma unroll
    for (int ii = 0; ii < 2; ++ii) {
      const int idx = ii * 256 + (w << 6) + l;
      {
        const int key = idx >> 3, pos = idx & 7;
        GLD_LDS16(qkv + ((size_t)b * S_ + kc + key) * 3072 + 1024 + h * 64 + ((pos ^ (key & 7)) << 3),
                  &kbuf[bf][(ii * 256 + (w << 6)) * 8]);
      }
      {
        const int hd = idx & 1, kr = (idx >> 1) & 3, db = (idx >> 3) & 3, kb = idx >> 5;
        GLD_LDS16(qkv + ((size_t)b * S_ + kc + (kb << 2) + kr) * 3072 + 2048 + h * 64 + (db << 4) + (hd << 3),
                  &vbuf[bf][(ii * 256 + (w << 6)) * 8]);
      }
    }
  };

  stage(0, 0);
  __syncthreads();
  int buf = 0;

  for (int kc = 0; kc < S_; kc += KVB) {
    if (kc + KVB < S_) stage(buf ^ 1, kc + KVB);

    f32x4 sacc[4];
    #pragma unroll
    for (int t = 0; t < 4; ++t) sacc[t] = f32x4{0.f, 0.f, 0.f, 0.f};
    #pragma unroll
    for (int t = 0; t < 4; ++t) {
      const int key = 16 * t + l15;
      #pragma unroll
      for (int s = 0; s < 2; ++s) {
        const bf16x8 kf = *(const bf16x8*)&kbuf[buf][key * 64 + ((((s << 2) + l4) ^ (key & 7)) << 3)];
        sacc[t] = __builtin_amdgcn_mfma_f32_16x16x32_bf16(kf, qf[s], sacc[t], 0, 0, 0);
      }
    }

    float sv[4][4]; float pmax = -3.0e38f;
    #pragma unroll
    for (int t = 0; t < 4; ++t) {
      const float4 mk = *(const float4*)(maskr + kc + 16 * t + (l4 << 2));
      sv[t][0] = sacc[t][0] * 0.125f + mk.x;
      sv[t][1] = sacc[t][1] * 0.125f + mk.y;
      sv[t][2] = sacc[t][2] * 0.125f + mk.z;
      sv[t][3] = sacc[t][3] * 0.125f + mk.w;
      pmax = fmaxf(pmax, fmaxf(fmaxf(sv[t][0], sv[t][1]), fmaxf(sv[t][2], sv[t][3])));
    }
    pmax = fmaxf(pmax, __shfl_xor(pmax, 16, 64));
    pmax = fmaxf(pmax, __shfl_xor(pmax, 32, 64));

    if (kc == 0) {
      mrun = pmax;
    } else if (!__all(pmax <= mrun + 2.0f)) {
      const float mn = fmaxf(mrun, pmax);
      const float f = __expf(mrun - mn);
      if (l4 == 0) smbuf[w][l15] = f;
      float fr[4];
      #pragma unroll
      for (int i = 0; i < 4; ++i) fr[i] = smbuf[w][(l4 << 2) + i];
      #pragma unroll
      for (int db = 0; db < 4; ++db)
        #pragma unroll
        for (int i = 0; i < 4; ++i) cacc[db][i] *= fr[i];
      lrun *= f;
      mrun = mn;
    }

    float p[4][4]; float lsum = 0.0f;
    #pragma unroll
    for (int t = 0; t < 4; ++t)
      #pragma unroll
      for (int i = 0; i < 4; ++i) { p[t][i] = __expf(sv[t][i] - mrun); lsum += p[t][i]; }
    lsum += __shfl_xor(lsum, 16, 64);
    lsum += __shfl_xor(lsum, 32, 64);
    lrun += lsum;

    #pragma unroll
    for (int t = 0; t < 4; ++t) {
      unsigned pa_, pc_;
      asm("v_cvt_pk_bf16_f32 %0, %1, %2" : "=v"(pa_) : "v"(p[t][0]), "v"(p[t][1]));
      asm("v_cvt_pk_bf16_f32 %0, %1, %2" : "=v"(pc_) : "v"(p[t][2]), "v"(p[t][3]));
      const int byte = l15 * 128 + ((((t << 1) + (l4 >> 1)) ^ (l15 & 7)) << 4) + ((l4 & 1) << 3);
      *(u32x2*)((char*)&plds[w][0] + byte) = (u32x2){pa_, pc_};
    }

    const unsigned vb_off = (unsigned)(uintptr_t)(__attribute__((address_space(3))) void*)&vbuf[buf][0];
    #pragma unroll
    for (int ks = 0; ks < 2; ++ks) {
      const bf16x8 pa = *(const bf16x8*)((char*)&plds[w][0] +
                          l15 * 128 + ((((ks << 2) + l4) ^ (l15 & 7)) << 4));
      u32x2 tv[4][2];
      #pragma unroll
      for (int db = 0; db < 4; ++db) {
        const unsigned va = vb_off + (unsigned)(((ks << 5) + 7 * l4 + db) << 7);
        asm volatile("ds_read_b64_tr_b16 %0, %2\n\t"
                     "ds_read_b64_tr_b16 %1, %2 offset:512"
                     : "=v"(tv[db][0]), "=v"(tv[db][1]) : "v"(va));
      }
      asm volatile("s_waitcnt lgkmcnt(0)" ::: "memory");
      __builtin_amdgcn_sched_barrier(0);
      #pragma unroll
      for (int db = 0; db < 4; ++db) {
        union { unsigned u[4]; bf16x8 v; } vb_;
        vb_.u[0] = tv[db][0].x; vb_.u[1] = tv[db][0].y;
        vb_.u[2] = tv[db][1].x; vb_.u[3] = tv[db][1].y;
        cacc[db] = __builtin_amdgcn_mfma_f32_16x16x32_bf16(pa, vb_.v, cacc[db], 0, 0, 0);
      }
    }
    __syncthreads();
    buf ^= 1;
  }

  if (l4 == 0) smbuf[w][l15] = 1.0f / lrun;
  float rl[4];
  #pragma unroll
  for (int i = 0; i < 4; ++i) rl[i] = smbuf[w][(l4 << 2) + i];
  #pragma unroll
  for (int db = 0; db < 4; ++db)
    #pragma unroll
    for (int i = 0; i < 4; ++i) {
      const size_t row = (size_t)b * S_ + qt + w * 16 + (l4 << 2) + i;
      ctx[row * 1024 + h * 64 + (db << 4) + l15] = f2bf(cacc[db][i] * rl[i]);
    }
}

// ---------------------------------------------------------------- layernorm
__global__ __launch_bounds__(256) void ln_kernel(
    const float* __restrict__ x, const float* __restrict__ resid,
    const float* __restrict__ gg, const float* __restrict__ bb,
    float* __restrict__ outf, u16* __restrict__ outb)
{
  const int row = blockIdx.x, t = threadIdx.x;
  const size_t off = (size_t)row * D_ + t * 4;
  const float4 a = *(const float4*)(x + off);
  const float4 r = *(const float4*)(resid + off);
  const float v0 = a.x + r.x, v1 = a.y + r.y, v2 = a.z + r.z, v3 = a.w + r.w;
  float s = v0 + v1 + v2 + v3;
  float s2 = v0*v0 + v1*v1 + v2*v2 + v3*v3;
  #pragma unroll
  for (int d = 1; d < 64; d <<= 1) {
    s += __shfl_xor(s, d, 64);
    s2 += __shfl_xor(s2, d, 64);
  }
  __shared__ float red[8];
  const int w = t >> 6, l = t & 63;
  if (l == 0) { red[w] = s; red[4 + w] = s2; }
  __syncthreads();
  s = red[0] + red[1] + red[2] + red[3];
  s2 = red[4] + red[5] + red[6] + red[7];
  const float mu = s * (1.0f / D_);
  const float rs = rsqrtf(s2 * (1.0f / D_) - mu * mu + 1e-6f);
  const float4 gv = *(const float4*)(gg + t * 4);
  const float4 bv = *(const float4*)(bb + t * 4);
  const float o0 = (v0 - mu) * rs * gv.x + bv.x;
  const float o1 = (v1 - mu) * rs * gv.y + bv.y;
  const float o2 = (v2 - mu) * rs * gv.z + bv.z;
  const float o3 = (v3 - mu) * rs * gv.w + bv.w;
  float4 o; o.x = o0; o.y = o1; o.z = o2; o.w = o3;
  *(float4*)(outf + off) = o;
  if (outb) {
    u16x4 ob = { f2bf(o0), f2bf(o1), f2bf(o2), f2bf(o3) };
    *(u16x4*)(outb + off) = ob;
  }
}

// ---------------------------------------------------------------- gate
__global__ __launch_bounds__(256) void gate_kernel(
    const float* __restrict__ inter, const float* __restrict__ gw,
    const float* __restrict__ gb, float* __restrict__ gout)
{
  const int w = threadIdx.x >> 6, l = threadIdx.x & 63;
  const int row = blockIdx.x * 4 + w;
  float acc[8] = {};
  const float* xr = inter + (size_t)row * D_;
  #pragma unroll 4
  for (int c = 0; c < 16; ++c) {
    const int kk = c * 64 + l;
    const float xv = xr[kk];
    const float4 g0 = *(const float4*)(gw + kk * 8);
    const float4 g1 = *(const float4*)(gw + kk * 8 + 4);
    acc[0] += xv * g0.x; acc[1] += xv * g0.y; acc[2] += xv * g0.z; acc[3] += xv * g0.w;
    acc[4] += xv * g1.x; acc[5] += xv * g1.y; acc[6] += xv * g1.z; acc[7] += xv * g1.w;
  }
  #pragma unroll
  for (int e = 0; e < 8; ++e)
    #pragma unroll
    for (int d = 1; d < 64; d <<= 1) acc[e] += __shfl_xor(acc[e], d, 64);
  float mx = -1e30f;
  #pragma unroll
  for (int e = 0; e < 8; ++e) { acc[e] += gb[e]; mx = fmaxf(mx, acc[e]); }
  float sum = 0.0f;
  #pragma unroll
  for (int e = 0; e < 8; ++e) { acc[e] = __expf(acc[e] - mx); sum += acc[e]; }
  const float inv = 1.0f / sum;
  if (l == 0) {
    #pragma unroll
    for (int e = 0; e < 8; ++e) gout[(size_t)row * 8 + e] = acc[e] * inv;
  }
}

// ---------------------------------------------------------------- launch
extern "C" void kernel_launch(void* const* d_in, const int* in_sizes, int n_in,
                              void* d_out, int out_size, void* d_ws, size_t ws_size,
                              hipStream_t stream) {
  const float* hidden = (const float*)d_in[0];
  const float* mask   = (const float*)d_in[1];
  const float* wq = (const float*)d_in[2];
  const float* bq = (const float*)d_in[3];
  const float* wk = (const float*)d_in[4];
  const float* bk = (const float*)d_in[5];
  const float* wv = (const float*)d_in[6];
  const float* bv = (const float*)d_in[7];
  const float* wo = (const float*)d_in[8];
  const float* bo = (const float*)d_in[9];
  const float* ln1g = (const float*)d_in[10];
  const float* ln1b = (const float*)d_in[11];
  const float* gw = (const float*)d_in[12];
  const float* gb = (const float*)d_in[13];
  const float* w1 = (const float*)d_in[14];
  const float* b1 = (const float*)d_in[15];
  const float* w2 = (const float*)d_in[16];
  const float* b2 = (const float*)d_in[17];
  const float* ln2g = (const float*)d_in[18];
  const float* ln2b = (const float*)d_in[19];

  float* out = (float*)d_out;
  float* gate_out = out + (size_t)M_ * D_;

  char* ws = (char*)d_ws;
  size_t off = 0;
  auto alloc = [&](size_t bytes) -> void* {
    void* p = ws + off;
    off += (bytes + 255) & ~(size_t)255;
    return p;
  };
  // persistent across phases
  float* inter = (float*)alloc((size_t)M_ * D_ * 4);
  u16* interb  = (u16*)alloc((size_t)M_ * D_ * 2);
  float* moe   = (float*)alloc((size_t)M_ * D_ * 4);
  const size_t mark = off;
  // attn-phase region
  u16* xb      = (u16*)alloc((size_t)M_ * D_ * 2);
  u16* wqkvt   = (u16*)alloc((size_t)3 * D_ * D_ * 2);
  float* bqkv  = (float*)alloc((size_t)3 * D_ * 4);
  u16* qkvb    = (u16*)alloc((size_t)M_ * 3 * D_ * 2);
  u16* wot     = (u16*)alloc((size_t)D_ * D_ * 2);
  u16* ctxb    = (u16*)alloc((size_t)M_ * D_ * 2);
  float* tmp   = (float*)alloc((size_t)M_ * D_ * 4);
  const size_t attn_end = off;
  // moe-phase plan A (aliases attn region)
  off = mark;
  u16* w1t   = (u16*)alloc((size_t)E_ * D_ * F_ * 2);           // [E][F][D]
  u16* w2t2  = (u16*)alloc((size_t)E_ * D_ * F_ * 2);           // [D][E*F]
  u16* hb    = (u16*)alloc((size_t)M_ * E_ * F_ * 2);           // [M][E*F]
  float* part= (float*)alloc((size_t)8 * M_ * D_ * 4);          // [8][M][D]
  const size_t planA_end = off;
  // moe-phase fallback
  off = mark;
  u16* w1tf = (u16*)alloc((size_t)D_ * F_ * 2);
  u16* w2tf = (u16*)alloc((size_t)D_ * F_ * 2);
  u16* hbf  = (u16*)alloc((size_t)M_ * F_ * 2);
  const bool planA = (planA_end <= ws_size) && (attn_end <= ws_size);

  const dim3 tb(32, 8);

  cvt_kernel<<<M_ * D_ / 1024, 256, 0, stream>>>(hidden, xb);
  transpose_cvt<<<dim3(D_/32, D_/32, 1), tb, 0, stream>>>(wq, wqkvt, D_, D_, D_, 0, 0);
  transpose_cvt<<<dim3(D_/32, D_/32, 1), tb, 0, stream>>>(wk, wqkvt + (size_t)D_*D_, D_, D_, D_, 0, 0);
  transpose_cvt<<<dim3(D_/32, D_/32, 1), tb, 0, stream>>>(wv, wqkvt + (size_t)2*D_*D_, D_, D_, D_, 0, 0);
  transpose_cvt<<<dim3(D_/32, D_/32, 1), tb, 0, stream>>>(wo, wot, D_, D_, D_, 0, 0);
  hipMemcpyAsync(bqkv,        bq, D_ * 4, hipMemcpyDeviceToDevice, stream);
  hipMemcpyAsync(bqkv + D_,   bk, D_ * 4, hipMemcpyDeviceToDevice, stream);
  hipMemcpyAsync(bqkv + 2*D_, bv, D_ * 4, hipMemcpyDeviceToDevice, stream);

  hipFuncSetAttribute((const void*)gemm256<EPI_BF16,0>, hipFuncAttributeMaxDynamicSharedMemorySize, 131072);
  hipFuncSetAttribute((const void*)gemm256<EPI_GG,1>,   hipFuncAttributeMaxDynamicSharedMemorySize, 131072);
  hipFuncSetAttribute((const void*)gemm256<EPI_PART,0>, hipFuncAttributeMaxDynamicSharedMemorySize, 131072);

  gemm256<EPI_BF16,0><<<dim3(3*D_/256, M_/256, 1), 512, 131072, stream>>>(
      xb, wqkvt, D_, D_, D_, 0, 0, 0, 0, bqkv, qkvb, 3*D_, nullptr);

  attn2_kernel<<<dim3(S_/64, H_, B_), 256, 0, stream>>>(qkvb, mask, ctxb);

  gemm_bf16<EPI_F32,false><<<dim3(D_/BM, M_/BM), 256, 0, stream>>>(ctxb, wot, D_, bo, tmp, D_, nullptr);

  ln_kernel<<<M_, 256, 0, stream>>>(tmp, hidden, ln1g, ln1b, inter, interb);
  gate_kernel<<<M_/4, 256, 0, stream>>>(inter, gw, gb, gate_out);

  if (planA) {
    transpose_cvt<<<dim3(F_/32, D_/32, E_), tb, 0, stream>>>(w1, w1t, D_, F_, D_, (long)D_*F_, (long)F_*D_);
    transpose_cvt<<<dim3(D_/32, F_/32, E_), tb, 0, stream>>>(w2, w2t2, F_, D_, E_*F_, (long)F_*D_, (long)F_);
    // GEMM1 (batched experts, expert-per-XCD swizzle)
    gemm256<EPI_GG,1><<<dim3(F_/256, M_/256, E_), 512, 131072, stream>>>(
        interb, w1t, D_, D_, D_, 0, (long)D_*F_, (long)F_, F_, b1, hb, E_*F_, gate_out);
    // GEMM2 split-K x8 over fused K = E*F = 32768 -> 512 blocks = 2/CU
    gemm256<EPI_PART,0><<<dim3(D_/256, M_/256, 8), 512, 131072, stream>>>(
        hb, w2t2, 4096, E_*F_, E_*F_, 4096, 4096, (long)M_*D_, 0, nullptr, part, D_, nullptr);
    moe_reduce<<<M_, 256, 0, stream>>>(part, gate_out, b2, moe);
  } else {
    for (int e = 0; e < E_; ++e) {
      transpose_cvt<<<dim3(F_/32, D_/32, 1), tb, 0, stream>>>(w1 + (size_t)e*D_*F_, w1tf, D_, F_, D_, 0, 0);
      transpose_cvt<<<dim3(D_/32, F_/32, 1), tb, 0, stream>>>(w2 + (size_t)e*F_*D_, w2tf, F_, D_, F_, 0, 0);
      gemm_bf16<EPI_GELU,false><<<dim3(F_/BM, M_/BM), 256, 0, stream>>>(interb, w1tf, D_, b1 + (size_t)e*F_, hbf, F_, nullptr);
      if (e == 0)
        gemm_bf16<EPI_MOE,true ><<<dim3(D_/BM, M_/BM), 256, 0, stream>>>(hbf, w2tf, F_, b2 + (size_t)e*D_, moe, D_, gate_out + e);
      else
        gemm_bf16<EPI_MOE,false><<<dim3(D_/BM, M_/BM), 256, 0, stream>>>(hbf, w2tf, F_, b2 + (size_t)e*D_, moe, D_, gate_out + e);
    }
  }

  ln_kernel<<<M_, 256, 0, stream>>>(moe, inter, ln2g, ln2b, out, nullptr);
}

// Round 10
// 957.565 us; speedup vs baseline: 1.4504x; 1.4504x over previous
//
#include <hip/hip_runtime.h>
#include <cstdint>

#define B_ 2
#define S_ 2048
#define D_ 1024
#define H_ 16
#define DH_ 64
#define F_ 4096
#define E_ 8
#define M_ (B_*S_)   // 4096 rows
#define KVB 64

using u16 = unsigned short;
typedef __bf16 bf16x8 __attribute__((ext_vector_type(8)));
typedef float f32x4 __attribute__((ext_vector_type(4)));
typedef u16 u16x8 __attribute__((ext_vector_type(8)));
typedef u16 u16x4 __attribute__((ext_vector_type(4)));
typedef unsigned int u32x2 __attribute__((ext_vector_type(2)));

__device__ __forceinline__ u16 f2bf(float f) {
  union { float f; uint32_t u; } x; x.f = f;
  uint32_t u = x.u;
  u += 0x7fffu + ((u >> 16) & 1u);   // RNE
  return (u16)(u >> 16);
}

#define GLD_LDS16(g, l) __builtin_amdgcn_global_load_lds( \
    (__attribute__((address_space(1))) void*)(g), \
    (__attribute__((address_space(3))) void*)(l), 16, 0, 0)

// ---------------------------------------------------------------- converts
__global__ __launch_bounds__(256) void cvt_kernel(const float* __restrict__ in,
                                                  u16* __restrict__ out) {
  const size_t i = ((size_t)blockIdx.x * 256 + threadIdx.x) * 4;
  float4 v = *(const float4*)(in + i);
  u16x4 o = { f2bf(v.x), f2bf(v.y), f2bf(v.z), f2bf(v.w) };
  *(u16x4*)(out + i) = o;
}

// in: [z][R][C] f32 -> out: z-th block, [C][R] bf16 with leading dim ldo.
__global__ __launch_bounds__(256) void transpose_cvt(const float* __restrict__ in,
                                                     u16* __restrict__ out,
                                                     int R, int C, int ldo,
                                                     long zin, long zout) {
  __shared__ u16 tile[32][33];
  in  += (size_t)blockIdx.z * zin;
  out += (size_t)blockIdx.z * zout;
  const int tx = threadIdx.x, ty = threadIdx.y;
  const int c0 = blockIdx.x * 32, r0 = blockIdx.y * 32;
  #pragma unroll
  for (int rr = ty; rr < 32; rr += 8)
    tile[rr][tx] = f2bf(in[(size_t)(r0 + rr) * C + c0 + tx]);
  __syncthreads();
  #pragma unroll
  for (int rr = ty; rr < 32; rr += 8)
    out[(size_t)(c0 + rr) * ldo + r0 + tx] = tile[tx][rr];
}

enum { EPI_BF16 = 0, EPI_F32 = 1, EPI_GELU = 2, EPI_MOE = 3, EPI_GG = 4, EPI_PART = 5 };

// ---------------------------------------------------------------- GEMM 128^2 (2-phase)
#define BM 128
#define BN 128
#define BK 64

template<int EPI, bool INIT>
__global__ __launch_bounds__(256, 2) void gemm_bf16(
    const u16* __restrict__ A, const u16* __restrict__ Bt, int K,
    const float* __restrict__ bias, void* __restrict__ outp, int ldc,
    const float* __restrict__ gate)
{
  __shared__ u16 ldsA[2][BM * BK];
  __shared__ u16 ldsB[2][BN * BK];
  const int tid = threadIdx.x;
  const int w = tid >> 6, l = tid & 63;
  const int tile_n = blockIdx.x * BN;
  const int tile_m = blockIdx.y * BM;
  const int wr = w >> 1, wc = w & 1;
  const int l15 = l & 15, l4 = l >> 4;

  f32x4 acc[4][4] = {};

  const int srow = (w << 5) + (l >> 3);
  const int schunk = (l & 7) ^ (l >> 3);
  const u16* srcA0 = A + (size_t)(tile_m + srow) * K + schunk * 8;
  const u16* srcB0 = Bt + (size_t)(tile_n + srow) * K + schunk * 8;

  auto stage = [&](int buf, int kt) {
    #pragma unroll
    for (int i = 0; i < 4; ++i) {
      GLD_LDS16(srcA0 + kt + (size_t)(i * 8) * K, &ldsA[buf][((w << 5) + i * 8) * BK]);
      GLD_LDS16(srcB0 + kt + (size_t)(i * 8) * K, &ldsB[buf][((w << 5) + i * 8) * BK]);
    }
  };

  auto compute = [&](int buf) {
    #pragma unroll
    for (int ks = 0; ks < 2; ++ks) {
      bf16x8 af[4], bfr[4];
      #pragma unroll
      for (int m = 0; m < 4; ++m) {
        const int r = wr * 64 + m * 16 + l15;
        const int c = ((ks << 2) + l4) ^ (r & 7);
        af[m] = *(const bf16x8*)&ldsA[buf][r * BK + c * 8];
      }
      #pragma unroll
      for (int n = 0; n < 4; ++n) {
        const int r = wc * 64 + n * 16 + l15;
        const int c = ((ks << 2) + l4) ^ (r & 7);
        bfr[n] = *(const bf16x8*)&ldsB[buf][r * BK + c * 8];
      }
      #pragma unroll
      for (int m = 0; m < 4; ++m)
        #pragma unroll
        for (int n = 0; n < 4; ++n)
          acc[m][n] = __builtin_amdgcn_mfma_f32_16x16x32_bf16(af[m], bfr[n], acc[m][n], 0, 0, 0);
    }
  };

  const int nT = K / BK;
  stage(0, 0);
  __syncthreads();
  int buf = 0;
  for (int t = 0; t < nT; ++t) {
    if (t + 1 < nT) stage(buf ^ 1, (t + 1) * BK);
    compute(buf);
    __syncthreads();
    buf ^= 1;
  }

  #pragma unroll
  for (int m = 0; m < 4; ++m) {
    const int row0 = tile_m + wr * 64 + m * 16 + (l4 << 2);
    #pragma unroll
    for (int n = 0; n < 4; ++n) {
      const int col = tile_n + wc * 64 + n * 16 + l15;
      const float bv = bias[col];
      #pragma unroll
      for (int i = 0; i < 4; ++i) {
        const int row = row0 + i;
        const float v = acc[m][n][i] + bv;
        const size_t idx = (size_t)row * ldc + col;
        if (EPI == EPI_BF16) {
          ((u16*)outp)[idx] = f2bf(v);
        } else if (EPI == EPI_F32) {
          ((float*)outp)[idx] = v;
        } else if (EPI == EPI_GELU) {
          const float e = __expf(-1.5957691216f * (v + 0.044715f * v * v * v));
          ((u16*)outp)[idx] = f2bf(v / (1.0f + e));
        } else if (EPI == EPI_MOE) {
          const float g = gate[(size_t)row * E_];
          float* o = (float*)outp;
          if (INIT) o[idx] = g * v;
          else      o[idx] += g * v;
        }
      }
    }
  }
}

// ---------------------------------------------------------------- GEMM 256^2, r5 8-phase (best measured)
#define RD_A8(BUF, MH) \
  _Pragma("unroll") for (int mm = 0; mm < 4; ++mm) \
    _Pragma("unroll") for (int ks = 0; ks < 2; ++ks) \
      af[mm][ks] = *(const bf16x8*)&ldsA[(BUF) * 16384 + (MH) * 8192 + \
        (((wr << 6) | (mm * 16 + l15)) << 6) + (((ks * 4 + l4) ^ (l15 & 7)) << 3)];
#define RD_B4(BUF, NH) \
  _Pragma("unroll") for (int nn = 0; nn < 2; ++nn) \
    _Pragma("unroll") for (int ks = 0; ks < 2; ++ks) \
      bfr[NH][nn][ks] = *(const bf16x8*)&ldsB[(BUF) * 16384 + (NH) * 8192 + \
        (((wc << 5) | (nn * 16 + l15)) << 6) + (((ks * 4 + l4) ^ (l15 & 7)) << 3)];
#define STAGE_A(Q, BUF, KT) \
  _Pragma("unroll") for (int j = 0; j < 2; ++j) \
    GLD_LDS16(Ag + (size_t)(tm + rgA[j][Q]) * lda + (KT) + scol, \
              &ldsA[(BUF) * 16384 + (Q) * 8192 + dstoff[j]]);
#define STAGE_B(Q, BUF, KT) \
  _Pragma("unroll") for (int j = 0; j < 2; ++j) \
    GLD_LDS16(Bg + (size_t)(tn + rgB[j][Q]) * ldb + (KT) + scol, \
              &ldsB[(BUF) * 16384 + (Q) * 8192 + dstoff[j]]);
#define MFMA_Q(MH, NH) \
  __builtin_amdgcn_s_setprio(1); \
  _Pragma("unroll") for (int mm = 0; mm < 4; ++mm) \
    _Pragma("unroll") for (int nn = 0; nn < 2; ++nn) \
      _Pragma("unroll") for (int ks = 0; ks < 2; ++ks) \
        acc[(MH)*4+mm][(NH)*2+nn] = __builtin_amdgcn_mfma_f32_16x16x32_bf16( \
            af[mm][ks], bfr[NH][nn][ks], acc[(MH)*4+mm][(NH)*2+nn], 0, 0, 0); \
  __builtin_amdgcn_s_setprio(0);
#define VMC6 asm volatile("s_waitcnt vmcnt(6)" ::: "memory")
#define VMC0 asm volatile("s_waitcnt vmcnt(0)" ::: "memory")
#define SCB  __builtin_amdgcn_sched_barrier(0)
#define BARR __builtin_amdgcn_s_barrier()
#define LGKM0 do { asm volatile("s_waitcnt lgkmcnt(0)" ::: "memory"); SCB; } while (0)

#define PH_TAIL(MH, NH) \
  SCB; BARR; LGKM0; MFMA_Q(MH, NH)

#define TILE_MAIN(BUF, KT1, KT2) \
  RD_A8(BUF, 0) RD_B4(BUF, 0) STAGE_A(1, (BUF) ^ 1, KT1) PH_TAIL(0, 0) BARR; \
  RD_B4(BUF, 1)               STAGE_A(0, BUF, KT2)       PH_TAIL(0, 1) BARR; \
  RD_A8(BUF, 1)               STAGE_B(0, BUF, KT2)       PH_TAIL(1, 0) BARR; \
                              STAGE_B(1, BUF, KT2)       PH_TAIL(1, 1) VMC6; BARR;

#define TILE_PEN(BUF, KT1) \
  RD_A8(BUF, 0) RD_B4(BUF, 0) STAGE_A(1, (BUF) ^ 1, KT1) PH_TAIL(0, 0) BARR; \
  RD_B4(BUF, 1)                                          PH_TAIL(0, 1) BARR; \
  RD_A8(BUF, 1)                                          PH_TAIL(1, 0) BARR; \
                                                         PH_TAIL(1, 1) VMC0; BARR;

#define TILE_LAST(BUF) \
  RD_A8(BUF, 0) RD_B4(BUF, 0) PH_TAIL(0, 0) BARR; \
  RD_B4(BUF, 1)               PH_TAIL(0, 1) BARR; \
  RD_A8(BUF, 1)               PH_TAIL(1, 0) BARR; \
                              PH_TAIL(1, 1)

template<int EPI>
__global__ __launch_bounds__(512, 2) void gemm256(
    const u16* __restrict__ A, const u16* __restrict__ Bt,
    const int K, const int lda, const int ldb,
    const long zA, const long zB, const long zC, const int zBias,
    const float* __restrict__ bias, void* __restrict__ outp, const int ldc,
    const float* __restrict__ gate)
{
  extern __shared__ u16 lds[];
  u16* ldsA = lds;            // [2][2][128][64]
  u16* ldsB = lds + 32768;
  const int tid = threadIdx.x, w = tid >> 6, l = tid & 63;
  const int wr = w >> 2, wc = w & 3;
  const int l15 = l & 15, l4 = l >> 4;

  // bijective XCD chunk swizzle (all launches have nwg % 8 == 0).
  // Note: for GG's grid (16,16,8) this pins expert z to XCD z (2048/8=256
  // blocks per chunk = exactly one z-slice).
  const unsigned nx = gridDim.x, ny = gridDim.y;
  const unsigned hw = blockIdx.x + nx * (blockIdx.y + ny * blockIdx.z);
  const unsigned nwg = nx * ny * gridDim.z;
  unsigned wg = (hw & 7u) * (nwg >> 3) + (hw >> 3);
  const unsigned bx = wg % nx;
  const unsigned rest = wg / nx;
  const unsigned by = rest % ny;
  const int z = (int)(rest / ny);

  const u16* Ag = A + (size_t)z * zA;
  const u16* Bg = Bt + (size_t)z * zB;
  const int tn = bx * 256, tm = by * 256;
  const int scol = ((l & 7) ^ (l >> 3)) * 8;

  f32x4 acc[8][4] = {};
  bf16x8 af[4][2];        // current A half
  bf16x8 bfr[2][2][2];    // both B halves resident

  int rgA[2][2], rgB[2][2], dstoff[2];
  #pragma unroll
  for (int j = 0; j < 2; ++j) {
    const int s = (j * 8 + w) * 8 + (l >> 3);
    dstoff[j] = (j * 8 + w) * 512;
    #pragma unroll
    for (int q = 0; q < 2; ++q) {
      rgA[j][q] = ((s >> 6) << 7) | (q << 6) | (s & 63);
      rgB[j][q] = ((s >> 5) << 6) | (q << 5) | (s & 31);
    }
  }

  // prologue FIFO: tile0 {A0,B0,B1,A1} -> buf0, tile1 {A0,B0,B1} -> buf1
  STAGE_A(0, 0, 0) STAGE_B(0, 0, 0) STAGE_B(1, 0, 0) STAGE_A(1, 0, 0)
  STAGE_A(0, 1, 64) STAGE_B(0, 1, 64) STAGE_B(1, 1, 64)
  VMC6;                       // tile0's 8 loads landed
  __syncthreads();

  const int nT = K / 64;      // even by construction
  for (int t = 0; t < nT - 2; t += 2) {
    TILE_MAIN(0, (t + 1) * 64, (t + 2) * 64)
    TILE_MAIN(1, (t + 2) * 64, (t + 3) * 64)
  }
  TILE_PEN(0, (nT - 1) * 64)  // tile nT-2
  TILE_LAST(1)                // tile nT-1

  // ---------------- epilogue
  if (EPI == EPI_BF16 || EPI == EPI_GG) {
    // coalesced bf16 store via LDS bounce: slab [32][260] f32 per (mh,mm)
    float* sl = (float*)lds;
    const int r2 = tid >> 4, c2 = (tid & 15) * 16;
    #pragma unroll
    for (int mh = 0; mh < 2; ++mh)
    #pragma unroll
    for (int mm = 0; mm < 4; ++mm) {
      BARR;
      #pragma unroll
      for (int nh = 0; nh < 2; ++nh)
      #pragma unroll
      for (int nn = 0; nn < 2; ++nn) {
        const f32x4 a = acc[mh * 4 + mm][nh * 2 + nn];
        const int c = wc * 64 + nh * 32 + nn * 16 + l15;
        #pragma unroll
        for (int i = 0; i < 4; ++i)
          sl[(wr * 16 + (l4 << 2) + i) * 260 + c] = a[i];
      }
      BARR;
      const int grow = tm + ((r2 >> 4) << 7) + mh * 64 + mm * 16 + (r2 & 15);
      float v[16];
      #pragma unroll
      for (int j = 0; j < 4; ++j) {
        const float4 tf = *(const float4*)&sl[r2 * 260 + c2 + j * 4];
        v[j*4+0] = tf.x; v[j*4+1] = tf.y; v[j*4+2] = tf.z; v[j*4+3] = tf.w;
      }
      u16 o[16];
      const float g = (EPI == EPI_GG) ? gate[(size_t)grow * E_ + z] : 0.0f;
      #pragma unroll
      for (int j = 0; j < 16; ++j) {
        float x = v[j] + bias[(EPI == EPI_GG ? z * zBias : 0) + tn + c2 + j];
        if (EPI == EPI_GG) {
          const float e = __expf(-1.5957691216f * (x + 0.044715f * x * x * x));
          x = (x / (1.0f + e)) * g;
        }
        o[j] = f2bf(x);
      }
      u16* dst = (u16*)outp + (size_t)z * zC + (size_t)grow * ldc + tn + c2;
      *(u16x8*)dst = *(const u16x8*)&o[0];
      *(u16x8*)(dst + 8) = *(const u16x8*)&o[8];
    }
  } else {  // EPI_PART: f32 direct
    #pragma unroll
    for (int mh = 0; mh < 2; ++mh)
    #pragma unroll
    for (int mm = 0; mm < 4; ++mm) {
      const int row0 = tm + wr * 128 + mh * 64 + mm * 16 + (l4 << 2);
      #pragma unroll
      for (int nh = 0; nh < 2; ++nh)
      #pragma unroll
      for (int nn = 0; nn < 2; ++nn) {
        const int col = tn + wc * 64 + nh * 32 + nn * 16 + l15;
        const f32x4 a = acc[mh * 4 + mm][nh * 2 + nn];
        #pragma unroll
        for (int i = 0; i < 4; ++i)
          ((float*)outp)[(size_t)z * zC + (size_t)(row0 + i) * ldc + col] = a[i];
      }
    }
  }
}
#undef RD_A8
#undef RD_B4
#undef STAGE_A
#undef STAGE_B
#undef MFMA_Q
#undef PH_TAIL
#undef TILE_MAIN
#undef TILE_PEN
#undef TILE_LAST

// ---------------------------------------------------------------- moe reduce (4 partials)
__global__ __launch_bounds__(256) void moe_reduce(
    const float* __restrict__ part, const float* __restrict__ gate,
    const float* __restrict__ b2, float* __restrict__ moe)
{
  const int row = blockIdx.x;
  const int c = threadIdx.x * 4;
  const size_t o = (size_t)row * D_ + c;
  float4 s = *(const float4*)(part + o);
  #pragma unroll
  for (int zz = 1; zz < 4; ++zz) {
    const float4 p = *(const float4*)(part + (size_t)zz * M_ * D_ + o);
    s.x += p.x; s.y += p.y; s.z += p.z; s.w += p.w;
  }
  #pragma unroll
  for (int e = 0; e < 8; ++e) {
    const float g = gate[(size_t)row * 8 + e];
    const float4 bv = *(const float4*)(b2 + (size_t)e * D_ + c);
    s.x += g * bv.x; s.y += g * bv.y; s.z += g * bv.z; s.w += g * bv.w;
  }
  *(float4*)(moe + o) = s;
}

// ---------------------------------------------------------------- attention
__global__ __launch_bounds__(256, 2) void attn2_kernel(
    const u16* __restrict__ qkv, const float* __restrict__ mask,
    u16* __restrict__ ctx)
{
  __shared__ u16 kbuf[2][KVB * 64];
  __shared__ u16 vbuf[2][KVB * 64];
  __shared__ __align__(16) u16 plds[4][16 * 64];
  __shared__ float smbuf[4][16];

  const int tid = threadIdx.x, w = tid >> 6, l = tid & 63;
  const int l15 = l & 15, l4 = l >> 4;

  // XCD swizzle: nwg = 32*16*2 = 1024
  unsigned wg = blockIdx.x + 32u * (blockIdx.y + 16u * blockIdx.z);
  wg = (wg & 7u) * 128u + (wg >> 3);
  const int qt = (int)(wg & 31u) * 64;
  const unsigned r1 = wg >> 5;
  const int h = (int)(r1 & 15u), b = (int)(r1 >> 4);

  const int qrow = qt + w * 16 + l15;
  const size_t grow = (size_t)b * S_ + qrow;
  bf16x8 qf[2];
  qf[0] = *(const bf16x8*)(qkv + grow * 3072 + h * 64 + l4 * 8);
  qf[1] = *(const bf16x8*)(qkv + grow * 3072 + h * 64 + 32 + l4 * 8);

  const float* maskr = mask + (size_t)b * S_ * S_ + (size_t)qrow * S_;

  f32x4 cacc[4] = {};
  float mrun = -3.0e38f, lrun = 0.0f;

  auto stage = [&](int bf, int kc) {
    #pragma unroll
    for (int ii = 0; ii < 2; ++ii) {
      const int idx = ii * 256 + (w << 6) + l;
      {
        const int key = idx >> 3, pos = idx & 7;
        GLD_LDS16(qkv + ((size_t)b * S_ + kc + key) * 3072 + 1024 + h * 64 + ((pos ^ (key & 7)) << 3),
                  &kbuf[bf][(ii * 256 + (w << 6)) * 8]);
      }
      {
        const int hd = idx & 1, kr = (idx >> 1) & 3, db = (idx >> 3) & 3, kb = idx >> 5;
        GLD_LDS16(qkv + ((size_t)b * S_ + kc + (kb << 2) + kr) * 3072 + 2048 + h * 64 + (db << 4) + (hd << 3),
                  &vbuf[bf][(ii * 256 + (w << 6)) * 8]);
      }
    }
  };

  stage(0, 0);
  __syncthreads();
  int buf = 0;

  for (int kc = 0; kc < S_; kc += KVB) {
    if (kc + KVB < S_) stage(buf ^ 1, kc + KVB);

    f32x4 sacc[4];
    #pragma unroll
    for (int t = 0; t < 4; ++t) sacc[t] = f32x4{0.f, 0.f, 0.f, 0.f};
    #pragma unroll
    for (int t = 0; t < 4; ++t) {
      const int key = 16 * t + l15;
      #pragma unroll
      for (int s = 0; s < 2; ++s) {
        const bf16x8 kf = *(const bf16x8*)&kbuf[buf][key * 64 + ((((s << 2) + l4) ^ (key & 7)) << 3)];
        sacc[t] = __builtin_amdgcn_mfma_f32_16x16x32_bf16(kf, qf[s], sacc[t], 0, 0, 0);
      }
    }

    float sv[4][4]; float pmax = -3.0e38f;
    #pragma unroll
    for (int t = 0; t < 4; ++t) {
      const float4 mk = *(const float4*)(maskr + kc + 16 * t + (l4 << 2));
      sv[t][0] = sacc[t][0] * 0.125f + mk.x;
      sv[t][1] = sacc[t][1] * 0.125f + mk.y;
      sv[t][2] = sacc[t][2] * 0.125f + mk.z;
      sv[t][3] = sacc[t][3] * 0.125f + mk.w;
      pmax = fmaxf(pmax, fmaxf(fmaxf(sv[t][0], sv[t][1]), fmaxf(sv[t][2], sv[t][3])));
    }
    pmax = fmaxf(pmax, __shfl_xor(pmax, 16, 64));
    pmax = fmaxf(pmax, __shfl_xor(pmax, 32, 64));

    if (kc == 0) {
      mrun = pmax;
    } else if (!__all(pmax <= mrun + 2.0f)) {
      const float mn = fmaxf(mrun, pmax);
      const float f = __expf(mrun - mn);
      if (l4 == 0) smbuf[w][l15] = f;
      float fr[4];
      #pragma unroll
      for (int i = 0; i < 4; ++i) fr[i] = smbuf[w][(l4 << 2) + i];
      #pragma unroll
      for (int db = 0; db < 4; ++db)
        #pragma unroll
        for (int i = 0; i < 4; ++i) cacc[db][i] *= fr[i];
      lrun *= f;
      mrun = mn;
    }

    float p[4][4]; float lsum = 0.0f;
    #pragma unroll
    for (int t = 0; t < 4; ++t)
      #pragma unroll
      for (int i = 0; i < 4; ++i) { p[t][i] = __expf(sv[t][i] - mrun); lsum += p[t][i]; }
    lsum += __shfl_xor(lsum, 16, 64);
    lsum += __shfl_xor(lsum, 32, 64);
    lrun += lsum;

    #pragma unroll
    for (int t = 0; t < 4; ++t) {
      unsigned pa_, pc_;
      asm("v_cvt_pk_bf16_f32 %0, %1, %2" : "=v"(pa_) : "v"(p[t][0]), "v"(p[t][1]));
      asm("v_cvt_pk_bf16_f32 %0, %1, %2" : "=v"(pc_) : "v"(p[t][2]), "v"(p[t][3]));
      const int byte = l15 * 128 + ((((t << 1) + (l4 >> 1)) ^ (l15 & 7)) << 4) + ((l4 & 1) << 3);
      *(u32x2*)((char*)&plds[w][0] + byte) = (u32x2){pa_, pc_};
    }

    const unsigned vb_off = (unsigned)(uintptr_t)(__attribute__((address_space(3))) void*)&vbuf[buf][0];
    #pragma unroll
    for (int ks = 0; ks < 2; ++ks) {
      const bf16x8 pa = *(const bf16x8*)((char*)&plds[w][0] +
                          l15 * 128 + ((((ks << 2) + l4) ^ (l15 & 7)) << 4));
      u32x2 tv[4][2];
      #pragma unroll
      for (int db = 0; db < 4; ++db) {
        const unsigned va = vb_off + (unsigned)(((ks << 5) + 7 * l4 + db) << 7);
        asm volatile("ds_read_b64_tr_b16 %0, %2\n\t"
                     "ds_read_b64_tr_b16 %1, %2 offset:512"
                     : "=v"(tv[db][0]), "=v"(tv[db][1]) : "v"(va));
      }
      asm volatile("s_waitcnt lgkmcnt(0)" ::: "memory");
      __builtin_amdgcn_sched_barrier(0);
      #pragma unroll
      for (int db = 0; db < 4; ++db) {
        union { unsigned u[4]; bf16x8 v; } vb_;
        vb_.u[0] = tv[db][0].x; vb_.u[1] = tv[db][0].y;
        vb_.u[2] = tv[db][1].x; vb_.u[3] = tv[db][1].y;
        cacc[db] = __builtin_amdgcn_mfma_f32_16x16x32_bf16(pa, vb_.v, cacc[db], 0, 0, 0);
      }
    }
    __syncthreads();
    buf ^= 1;
  }

  if (l4 == 0) smbuf[w][l15] = 1.0f / lrun;
  float rl[4];
  #pragma unroll
  for (int i = 0; i < 4; ++i) rl[i] = smbuf[w][(l4 << 2) + i];
  #pragma unroll
  for (int db = 0; db < 4; ++db)
    #pragma unroll
    for (int i = 0; i < 4; ++i) {
      const size_t row = (size_t)b * S_ + qt + w * 16 + (l4 << 2) + i;
      ctx[row * 1024 + h * 64 + (db << 4) + l15] = f2bf(cacc[db][i] * rl[i]);
    }
}

// ---------------------------------------------------------------- layernorm
__global__ __launch_bounds__(256) void ln_kernel(
    const float* __restrict__ x, const float* __restrict__ resid,
    const float* __restrict__ gg, const float* __restrict__ bb,
    float* __restrict__ outf, u16* __restrict__ outb)
{
  const int row = blockIdx.x, t = threadIdx.x;
  const size_t off = (size_t)row * D_ + t * 4;
  const float4 a = *(const float4*)(x + off);
  const float4 r = *(const float4*)(resid + off);
  const float v0 = a.x + r.x, v1 = a.y + r.y, v2 = a.z + r.z, v3 = a.w + r.w;
  float s = v0 + v1 + v2 + v3;
  float s2 = v0*v0 + v1*v1 + v2*v2 + v3*v3;
  #pragma unroll
  for (int d = 1; d < 64; d <<= 1) {
    s += __shfl_xor(s, d, 64);
    s2 += __shfl_xor(s2, d, 64);
  }
  __shared__ float red[8];
  const int w = t >> 6, l = t & 63;
  if (l == 0) { red[w] = s; red[4 + w] = s2; }
  __syncthreads();
  s = red[0] + red[1] + red[2] + red[3];
  s2 = red[4] + red[5] + red[6] + red[7];
  const float mu = s * (1.0f / D_);
  const float rs = rsqrtf(s2 * (1.0f / D_) - mu * mu + 1e-6f);
  const float4 gv = *(const float4*)(gg + t * 4);
  const float4 bv = *(const float4*)(bb + t * 4);
  const float o0 = (v0 - mu) * rs * gv.x + bv.x;
  const float o1 = (v1 - mu) * rs * gv.y + bv.y;
  const float o2 = (v2 - mu) * rs * gv.z + bv.z;
  const float o3 = (v3 - mu) * rs * gv.w + bv.w;
  float4 o; o.x = o0; o.y = o1; o.z = o2; o.w = o3;
  *(float4*)(outf + off) = o;
  if (outb) {
    u16x4 ob = { f2bf(o0), f2bf(o1), f2bf(o2), f2bf(o3) };
    *(u16x4*)(outb + off) = ob;
  }
}

// ---------------------------------------------------------------- gate
__global__ __launch_bounds__(256) void gate_kernel(
    const float* __restrict__ inter, const float* __restrict__ gw,
    const float* __restrict__ gb, float* __restrict__ gout)
{
  const int w = threadIdx.x >> 6, l = threadIdx.x & 63;
  const int row = blockIdx.x * 4 + w;
  float acc[8] = {};
  const float* xr = inter + (size_t)row * D_;
  #pragma unroll 4
  for (int c = 0; c < 16; ++c) {
    const int kk = c * 64 + l;
    const float xv = xr[kk];
    const float4 g0 = *(const float4*)(gw + kk * 8);
    const float4 g1 = *(const float4*)(gw + kk * 8 + 4);
    acc[0] += xv * g0.x; acc[1] += xv * g0.y; acc[2] += xv * g0.z; acc[3] += xv * g0.w;
    acc[4] += xv * g1.x; acc[5] += xv * g1.y; acc[6] += xv * g1.z; acc[7] += xv * g1.w;
  }
  #pragma unroll
  for (int e = 0; e < 8; ++e)
    #pragma unroll
    for (int d = 1; d < 64; d <<= 1) acc[e] += __shfl_xor(acc[e], d, 64);
  float mx = -1e30f;
  #pragma unroll
  for (int e = 0; e < 8; ++e) { acc[e] += gb[e]; mx = fmaxf(mx, acc[e]); }
  float sum = 0.0f;
  #pragma unroll
  for (int e = 0; e < 8; ++e) { acc[e] = __expf(acc[e] - mx); sum += acc[e]; }
  const float inv = 1.0f / sum;
  if (l == 0) {
    #pragma unroll
    for (int e = 0; e < 8; ++e) gout[(size_t)row * 8 + e] = acc[e] * inv;
  }
}

// ---------------------------------------------------------------- launch
extern "C" void kernel_launch(void* const* d_in, const int* in_sizes, int n_in,
                              void* d_out, int out_size, void* d_ws, size_t ws_size,
                              hipStream_t stream) {
  const float* hidden = (const float*)d_in[0];
  const float* mask   = (const float*)d_in[1];
  const float* wq = (const float*)d_in[2];
  const float* bq = (const float*)d_in[3];
  const float* wk = (const float*)d_in[4];
  const float* bk = (const float*)d_in[5];
  const float* wv = (const float*)d_in[6];
  const float* bv = (const float*)d_in[7];
  const float* wo = (const float*)d_in[8];
  const float* bo = (const float*)d_in[9];
  const float* ln1g = (const float*)d_in[10];
  const float* ln1b = (const float*)d_in[11];
  const float* gw = (const float*)d_in[12];
  const float* gb = (const float*)d_in[13];
  const float* w1 = (const float*)d_in[14];
  const float* b1 = (const float*)d_in[15];
  const float* w2 = (const float*)d_in[16];
  const float* b2 = (const float*)d_in[17];
  const float* ln2g = (const float*)d_in[18];
  const float* ln2b = (const float*)d_in[19];

  float* out = (float*)d_out;
  float* gate_out = out + (size_t)M_ * D_;

  char* ws = (char*)d_ws;
  size_t off = 0;
  auto alloc = [&](size_t bytes) -> void* {
    void* p = ws + off;
    off += (bytes + 255) & ~(size_t)255;
    return p;
  };
  // persistent across phases
  float* inter = (float*)alloc((size_t)M_ * D_ * 4);
  u16* interb  = (u16*)alloc((size_t)M_ * D_ * 2);
  float* moe   = (float*)alloc((size_t)M_ * D_ * 4);
  const size_t mark = off;
  // attn-phase region
  u16* xb      = (u16*)alloc((size_t)M_ * D_ * 2);
  u16* wqkvt   = (u16*)alloc((size_t)3 * D_ * D_ * 2);
  float* bqkv  = (float*)alloc((size_t)3 * D_ * 4);
  u16* qkvb    = (u16*)alloc((size_t)M_ * 3 * D_ * 2);
  u16* wot     = (u16*)alloc((size_t)D_ * D_ * 2);
  u16* ctxb    = (u16*)alloc((size_t)M_ * D_ * 2);
  float* tmp   = (float*)alloc((size_t)M_ * D_ * 4);
  const size_t attn_end = off;
  // moe-phase plan A (aliases attn region).
  // part[4][M][D] f32 (64 MiB) ALIASES w1t (64 MiB): w1t is dead once GG
  // completes, and PART reads only hb/w2t2. Keeps planA under ~464 MB
  // (r8/r9 lesson: part[8] pushed planA_end past ws_size -> silent planB).
  off = mark;
  u16* w1t   = (u16*)alloc((size_t)E_ * D_ * F_ * 2);           // [E][F][D]
  u16* w2t2  = (u16*)alloc((size_t)E_ * D_ * F_ * 2);           // [D][E*F]
  u16* hb    = (u16*)alloc((size_t)M_ * E_ * F_ * 2);           // [M][E*F]
  float* part = (float*)w1t;                                    // [4][M][D] alias
  const size_t planA_end = off;
  // moe-phase fallback
  off = mark;
  u16* w1tf = (u16*)alloc((size_t)D_ * F_ * 2);
  u16* w2tf = (u16*)alloc((size_t)D_ * F_ * 2);
  u16* hbf  = (u16*)alloc((size_t)M_ * F_ * 2);
  const bool planA = (planA_end <= ws_size) && (attn_end <= ws_size);

  const dim3 tb(32, 8);

  cvt_kernel<<<M_ * D_ / 1024, 256, 0, stream>>>(hidden, xb);
  transpose_cvt<<<dim3(D_/32, D_/32, 1), tb, 0, stream>>>(wq, wqkvt, D_, D_, D_, 0, 0);
  transpose_cvt<<<dim3(D_/32, D_/32, 1), tb, 0, stream>>>(wk, wqkvt + (size_t)D_*D_, D_, D_, D_, 0, 0);
  transpose_cvt<<<dim3(D_/32, D_/32, 1), tb, 0, stream>>>(wv, wqkvt + (size_t)2*D_*D_, D_, D_, D_, 0, 0);
  transpose_cvt<<<dim3(D_/32, D_/32, 1), tb, 0, stream>>>(wo, wot, D_, D_, D_, 0, 0);
  hipMemcpyAsync(bqkv,        bq, D_ * 4, hipMemcpyDeviceToDevice, stream);
  hipMemcpyAsync(bqkv + D_,   bk, D_ * 4, hipMemcpyDeviceToDevice, stream);
  hipMemcpyAsync(bqkv + 2*D_, bv, D_ * 4, hipMemcpyDeviceToDevice, stream);

  hipFuncSetAttribute((const void*)gemm256<EPI_BF16>, hipFuncAttributeMaxDynamicSharedMemorySize, 131072);
  hipFuncSetAttribute((const void*)gemm256<EPI_GG>,   hipFuncAttributeMaxDynamicSharedMemorySize, 131072);
  hipFuncSetAttribute((const void*)gemm256<EPI_PART>, hipFuncAttributeMaxDynamicSharedMemorySize, 131072);

  gemm256<EPI_BF16><<<dim3(3*D_/256, M_/256, 1), 512, 131072, stream>>>(
      xb, wqkvt, D_, D_, D_, 0, 0, 0, 0, bqkv, qkvb, 3*D_, nullptr);

  attn2_kernel<<<dim3(S_/64, H_, B_), 256, 0, stream>>>(qkvb, mask, ctxb);

  gemm_bf16<EPI_F32,false><<<dim3(D_/BM, M_/BM), 256, 0, stream>>>(ctxb, wot, D_, bo, tmp, D_, nullptr);

  ln_kernel<<<M_, 256, 0, stream>>>(tmp, hidden, ln1g, ln1b, inter, interb);
  gate_kernel<<<M_/4, 256, 0, stream>>>(inter, gw, gb, gate_out);

  if (planA) {
    transpose_cvt<<<dim3(F_/32, D_/32, E_), tb, 0, stream>>>(w1, w1t, D_, F_, D_, (long)D_*F_, (long)F_*D_);
    transpose_cvt<<<dim3(D_/32, F_/32, E_), tb, 0, stream>>>(w2, w2t2, F_, D_, E_*F_, (long)F_*D_, (long)F_);
    // GEMM1 (batched experts): hb[r][e*F+f] = gate_e(r)*gelu(interb@w1_e + b1_e)
    gemm256<EPI_GG><<<dim3(F_/256, M_/256, E_), 512, 131072, stream>>>(
        interb, w1t, D_, D_, D_, 0, (long)D_*F_, (long)F_, F_, b1, hb, E_*F_, gate_out);
    // GEMM2 split-K x4 over fused K = E*F = 32768 (part aliases dead w1t)
    gemm256<EPI_PART><<<dim3(D_/256, M_/256, 4), 512, 131072, stream>>>(
        hb, w2t2, 8192, E_*F_, E_*F_, 8192, 8192, (long)M_*D_, 0, nullptr, part, D_, nullptr);
    moe_reduce<<<M_, 256, 0, stream>>>(part, gate_out, b2, moe);
  } else {
    for (int e = 0; e < E_; ++e) {
      transpose_cvt<<<dim3(F_/32, D_/32, 1), tb, 0, stream>>>(w1 + (size_t)e*D_*F_, w1tf, D_, F_, D_, 0, 0);
      transpose_cvt<<<dim3(D_/32, F_/32, 1), tb, 0, stream>>>(w2 + (size_t)e*F_*D_, w2tf, F_, D_, F_, 0, 0);
      gemm_bf16<EPI_GELU,false><<<dim3(F_/BM, M_/BM), 256, 0, stream>>>(interb, w1tf, D_, b1 + (size_t)e*F_, hbf, F_, nullptr);
      if (e == 0)
        gemm_bf16<EPI_MOE,true ><<<dim3(D_/BM, M_/BM), 256, 0, stream>>>(hbf, w2tf, F_, b2 + (size_t)e*D_, moe, D_, gate_out + e);
      else
        gemm_bf16<EPI_MOE,false><<<dim3(D_/BM, M_/BM), 256, 0, stream>>>(hbf, w2tf, F_, b2 + (size_t)e*D_, moe, D_, gate_out + e);
    }
  }

  ln_kernel<<<M_, 256, 0, stream>>>(moe, inter, ln2g, ln2b, out, nullptr);
}

// Round 11
// 929.447 us; speedup vs baseline: 1.4942x; 1.0303x over previous
//
#include <hip/hip_runtime.h>
#include <cstdint>

#define B_ 2
#define S_ 2048
#define D_ 1024
#define H_ 16
#define DH_ 64
#define F_ 4096
#define E_ 8
#define M_ (B_*S_)   // 4096 rows
#define KVB 64

using u16 = unsigned short;
typedef __bf16 bf16x8 __attribute__((ext_vector_type(8)));
typedef float f32x4 __attribute__((ext_vector_type(4)));
typedef u16 u16x8 __attribute__((ext_vector_type(8)));
typedef u16 u16x4 __attribute__((ext_vector_type(4)));
typedef unsigned int u32x2 __attribute__((ext_vector_type(2)));

__device__ __forceinline__ u16 f2bf(float f) {
  union { float f; uint32_t u; } x; x.f = f;
  uint32_t u = x.u;
  u += 0x7fffu + ((u >> 16) & 1u);   // RNE
  return (u16)(u >> 16);
}

#define GLD_LDS16(g, l) __builtin_amdgcn_global_load_lds( \
    (__attribute__((address_space(1))) void*)(g), \
    (__attribute__((address_space(3))) void*)(l), 16, 0, 0)

// ---------------------------------------------------------------- converts
__global__ __launch_bounds__(256) void cvt_kernel(const float* __restrict__ in,
                                                  u16* __restrict__ out) {
  const size_t i = ((size_t)blockIdx.x * 256 + threadIdx.x) * 4;
  float4 v = *(const float4*)(in + i);
  u16x4 o = { f2bf(v.x), f2bf(v.y), f2bf(v.z), f2bf(v.w) };
  *(u16x4*)(out + i) = o;
}

// in: [z][R][C] f32 -> out: z-th block, [C][R] bf16 with leading dim ldo.
__global__ __launch_bounds__(256) void transpose_cvt(const float* __restrict__ in,
                                                     u16* __restrict__ out,
                                                     int R, int C, int ldo,
                                                     long zin, long zout) {
  __shared__ u16 tile[32][33];
  in  += (size_t)blockIdx.z * zin;
  out += (size_t)blockIdx.z * zout;
  const int tx = threadIdx.x, ty = threadIdx.y;
  const int c0 = blockIdx.x * 32, r0 = blockIdx.y * 32;
  #pragma unroll
  for (int rr = ty; rr < 32; rr += 8)
    tile[rr][tx] = f2bf(in[(size_t)(r0 + rr) * C + c0 + tx]);
  __syncthreads();
  #pragma unroll
  for (int rr = ty; rr < 32; rr += 8)
    out[(size_t)(c0 + rr) * ldo + r0 + tx] = tile[tx][rr];
}

enum { EPI_BF16 = 0, EPI_F32 = 1, EPI_GELU = 2, EPI_MOE = 3, EPI_GG = 4, EPI_PART = 5 };

// ---------------------------------------------------------------- GEMM 128^2 (2-phase)
#define BM 128
#define BN 128
#define BK 64

template<int EPI, bool INIT>
__global__ __launch_bounds__(256, 2) void gemm_bf16(
    const u16* __restrict__ A, const u16* __restrict__ Bt, int K,
    const float* __restrict__ bias, void* __restrict__ outp, int ldc,
    const float* __restrict__ gate)
{
  __shared__ u16 ldsA[2][BM * BK];
  __shared__ u16 ldsB[2][BN * BK];
  const int tid = threadIdx.x;
  const int w = tid >> 6, l = tid & 63;
  const int tile_n = blockIdx.x * BN;
  const int tile_m = blockIdx.y * BM;
  const int wr = w >> 1, wc = w & 1;
  const int l15 = l & 15, l4 = l >> 4;

  f32x4 acc[4][4] = {};

  const int srow = (w << 5) + (l >> 3);
  const int schunk = (l & 7) ^ (l >> 3);
  const u16* srcA0 = A + (size_t)(tile_m + srow) * K + schunk * 8;
  const u16* srcB0 = Bt + (size_t)(tile_n + srow) * K + schunk * 8;

  auto stage = [&](int buf, int kt) {
    #pragma unroll
    for (int i = 0; i < 4; ++i) {
      GLD_LDS16(srcA0 + kt + (size_t)(i * 8) * K, &ldsA[buf][((w << 5) + i * 8) * BK]);
      GLD_LDS16(srcB0 + kt + (size_t)(i * 8) * K, &ldsB[buf][((w << 5) + i * 8) * BK]);
    }
  };

  auto compute = [&](int buf) {
    #pragma unroll
    for (int ks = 0; ks < 2; ++ks) {
      bf16x8 af[4], bfr[4];
      #pragma unroll
      for (int m = 0; m < 4; ++m) {
        const int r = wr * 64 + m * 16 + l15;
        const int c = ((ks << 2) + l4) ^ (r & 7);
        af[m] = *(const bf16x8*)&ldsA[buf][r * BK + c * 8];
      }
      #pragma unroll
      for (int n = 0; n < 4; ++n) {
        const int r = wc * 64 + n * 16 + l15;
        const int c = ((ks << 2) + l4) ^ (r & 7);
        bfr[n] = *(const bf16x8*)&ldsB[buf][r * BK + c * 8];
      }
      #pragma unroll
      for (int m = 0; m < 4; ++m)
        #pragma unroll
        for (int n = 0; n < 4; ++n)
          acc[m][n] = __builtin_amdgcn_mfma_f32_16x16x32_bf16(af[m], bfr[n], acc[m][n], 0, 0, 0);
    }
  };

  const int nT = K / BK;
  stage(0, 0);
  __syncthreads();
  int buf = 0;
  for (int t = 0; t < nT; ++t) {
    if (t + 1 < nT) stage(buf ^ 1, (t + 1) * BK);
    compute(buf);
    __syncthreads();
    buf ^= 1;
  }

  #pragma unroll
  for (int m = 0; m < 4; ++m) {
    const int row0 = tile_m + wr * 64 + m * 16 + (l4 << 2);
    #pragma unroll
    for (int n = 0; n < 4; ++n) {
      const int col = tile_n + wc * 64 + n * 16 + l15;
      const float bv = bias[col];
      #pragma unroll
      for (int i = 0; i < 4; ++i) {
        const int row = row0 + i;
        const float v = acc[m][n][i] + bv;
        const size_t idx = (size_t)row * ldc + col;
        if (EPI == EPI_BF16) {
          ((u16*)outp)[idx] = f2bf(v);
        } else if (EPI == EPI_F32) {
          ((float*)outp)[idx] = v;
        } else if (EPI == EPI_GELU) {
          const float e = __expf(-1.5957691216f * (v + 0.044715f * v * v * v));
          ((u16*)outp)[idx] = f2bf(v / (1.0f + e));
        } else if (EPI == EPI_MOE) {
          const float g = gate[(size_t)row * E_];
          float* o = (float*)outp;
          if (INIT) o[idx] = g * v;
          else      o[idx] += g * v;
        }
      }
    }
  }
}

// ---------------------------------------------------------------- GEMM 256^2, 2-phase (m97 structure at 256^2)
// 512 thr = 8 waves (2x4), per-wave 128x64. LDS 128KiB: A,B each
// [2 buf][2 half][128 slots][64], XOR-swizzled 16B chunks (r5 layout kept).
// m97-proven loop shape: stage ENTIRE next tile -> buf^1 (never the live
// buffer -> race-free with ONE syncthreads per tile); compute straight-line
// (no intra-tile fences: compiler emits fine-grained lgkmcnt so ds_reads
// hide under MFMA). Compiler's vmcnt(0) before the barrier is ~free: loads
// are issued a full tile (>=2500 cyc) ahead of the wait.
#define RD_A8(BUF, MH) \
  _Pragma("unroll") for (int mm = 0; mm < 4; ++mm) \
    _Pragma("unroll") for (int ks = 0; ks < 2; ++ks) \
      af[mm][ks] = *(const bf16x8*)&ldsA[(BUF) * 16384 + (MH) * 8192 + \
        (((wr << 6) | (mm * 16 + l15)) << 6) + (((ks * 4 + l4) ^ (l15 & 7)) << 3)];
#define RD_B4(BUF, NH) \
  _Pragma("unroll") for (int nn = 0; nn < 2; ++nn) \
    _Pragma("unroll") for (int ks = 0; ks < 2; ++ks) \
      bfr[NH][nn][ks] = *(const bf16x8*)&ldsB[(BUF) * 16384 + (NH) * 8192 + \
        (((wc << 5) | (nn * 16 + l15)) << 6) + (((ks * 4 + l4) ^ (l15 & 7)) << 3)];
#define STAGE_A(Q, BUF, KT) \
  _Pragma("unroll") for (int j = 0; j < 2; ++j) \
    GLD_LDS16(Ag + (size_t)(tm + rgA[j][Q]) * lda + (KT) + scol, \
              &ldsA[(BUF) * 16384 + (Q) * 8192 + dstoff[j]]);
#define STAGE_B(Q, BUF, KT) \
  _Pragma("unroll") for (int j = 0; j < 2; ++j) \
    GLD_LDS16(Bg + (size_t)(tn + rgB[j][Q]) * ldb + (KT) + scol, \
              &ldsB[(BUF) * 16384 + (Q) * 8192 + dstoff[j]]);
#define STAGE_ALL(BUF, KT) \
  STAGE_A(0, BUF, KT) STAGE_B(0, BUF, KT) STAGE_B(1, BUF, KT) STAGE_A(1, BUF, KT)
#define MFMA_Q(MH, NH) \
  __builtin_amdgcn_s_setprio(1); \
  _Pragma("unroll") for (int mm = 0; mm < 4; ++mm) \
    _Pragma("unroll") for (int nn = 0; nn < 2; ++nn) \
      _Pragma("unroll") for (int ks = 0; ks < 2; ++ks) \
        acc[(MH)*4+mm][(NH)*2+nn] = __builtin_amdgcn_mfma_f32_16x16x32_bf16( \
            af[mm][ks], bfr[NH][nn][ks], acc[(MH)*4+mm][(NH)*2+nn], 0, 0, 0); \
  __builtin_amdgcn_s_setprio(0);
#define BARR __builtin_amdgcn_s_barrier()

template<int EPI>
__global__ __launch_bounds__(512, 2) void gemm256(
    const u16* __restrict__ A, const u16* __restrict__ Bt,
    const int K, const int lda, const int ldb,
    const long zA, const long zB, const long zC, const int zBias,
    const float* __restrict__ bias, void* __restrict__ outp, const int ldc,
    const float* __restrict__ gate)
{
  extern __shared__ u16 lds[];
  u16* ldsA = lds;            // [2][2][128][64]
  u16* ldsB = lds + 32768;
  const int tid = threadIdx.x, w = tid >> 6, l = tid & 63;
  const int wr = w >> 2, wc = w & 3;
  const int l15 = l & 15, l4 = l >> 4;

  // bijective XCD chunk swizzle (all launches have nwg % 8 == 0).
  const unsigned nx = gridDim.x, ny = gridDim.y;
  const unsigned hw = blockIdx.x + nx * (blockIdx.y + ny * blockIdx.z);
  const unsigned nwg = nx * ny * gridDim.z;
  unsigned wg = (hw & 7u) * (nwg >> 3) + (hw >> 3);
  const unsigned bx = wg % nx;
  const unsigned rest = wg / nx;
  const unsigned by = rest % ny;
  const int z = (int)(rest / ny);

  const u16* Ag = A + (size_t)z * zA;
  const u16* Bg = Bt + (size_t)z * zB;
  const int tn = bx * 256, tm = by * 256;
  const int scol = ((l & 7) ^ (l >> 3)) * 8;

  f32x4 acc[8][4] = {};
  bf16x8 af[4][2];        // current A half
  bf16x8 bfr[2][2][2];    // both B halves resident

  int rgA[2][2], rgB[2][2], dstoff[2];
  #pragma unroll
  for (int j = 0; j < 2; ++j) {
    const int s = (j * 8 + w) * 8 + (l >> 3);
    dstoff[j] = (j * 8 + w) * 512;
    #pragma unroll
    for (int q = 0; q < 2; ++q) {
      rgA[j][q] = ((s >> 6) << 7) | (q << 6) | (s & 63);
      rgB[j][q] = ((s >> 5) << 6) | (q << 5) | (s & 31);
    }
  }

  // prologue: tile 0 -> buf0
  STAGE_ALL(0, 0)
  __syncthreads();

  const int nT = K / 64;
  int buf = 0;
  for (int t = 0; t < nT; ++t) {
    if (t + 1 < nT) { STAGE_ALL(buf ^ 1, (t + 1) * 64) }
    RD_A8(buf, 0) RD_B4(buf, 0) MFMA_Q(0, 0)
    RD_B4(buf, 1)               MFMA_Q(0, 1)
    RD_A8(buf, 1)               MFMA_Q(1, 0)
                                MFMA_Q(1, 1)
    __syncthreads();
    buf ^= 1;
  }

  // ---------------- epilogue
  if (EPI == EPI_BF16 || EPI == EPI_GG) {
    // coalesced bf16 store via LDS bounce: slab [32][260] f32 per (mh,mm)
    float* sl = (float*)lds;
    const int r2 = tid >> 4, c2 = (tid & 15) * 16;
    #pragma unroll
    for (int mh = 0; mh < 2; ++mh)
    #pragma unroll
    for (int mm = 0; mm < 4; ++mm) {
      BARR;
      #pragma unroll
      for (int nh = 0; nh < 2; ++nh)
      #pragma unroll
      for (int nn = 0; nn < 2; ++nn) {
        const f32x4 a = acc[mh * 4 + mm][nh * 2 + nn];
        const int c = wc * 64 + nh * 32 + nn * 16 + l15;
        #pragma unroll
        for (int i = 0; i < 4; ++i)
          sl[(wr * 16 + (l4 << 2) + i) * 260 + c] = a[i];
      }
      BARR;
      const int grow = tm + ((r2 >> 4) << 7) + mh * 64 + mm * 16 + (r2 & 15);
      float v[16];
      #pragma unroll
      for (int j = 0; j < 4; ++j) {
        const float4 tf = *(const float4*)&sl[r2 * 260 + c2 + j * 4];
        v[j*4+0] = tf.x; v[j*4+1] = tf.y; v[j*4+2] = tf.z; v[j*4+3] = tf.w;
      }
      u16 o[16];
      const float g = (EPI == EPI_GG) ? gate[(size_t)grow * E_ + z] : 0.0f;
      #pragma unroll
      for (int j = 0; j < 16; ++j) {
        float x = v[j] + bias[(EPI == EPI_GG ? z * zBias : 0) + tn + c2 + j];
        if (EPI == EPI_GG) {
          const float e = __expf(-1.5957691216f * (x + 0.044715f * x * x * x));
          x = (x / (1.0f + e)) * g;
        }
        o[j] = f2bf(x);
      }
      u16* dst = (u16*)outp + (size_t)z * zC + (size_t)grow * ldc + tn + c2;
      *(u16x8*)dst = *(const u16x8*)&o[0];
      *(u16x8*)(dst + 8) = *(const u16x8*)&o[8];
    }
  } else {  // EPI_PART: f32 direct
    #pragma unroll
    for (int mh = 0; mh < 2; ++mh)
    #pragma unroll
    for (int mm = 0; mm < 4; ++mm) {
      const int row0 = tm + wr * 128 + mh * 64 + mm * 16 + (l4 << 2);
      #pragma unroll
      for (int nh = 0; nh < 2; ++nh)
      #pragma unroll
      for (int nn = 0; nn < 2; ++nn) {
        const int col = tn + wc * 64 + nh * 32 + nn * 16 + l15;
        const f32x4 a = acc[mh * 4 + mm][nh * 2 + nn];
        #pragma unroll
        for (int i = 0; i < 4; ++i)
          ((float*)outp)[(size_t)z * zC + (size_t)(row0 + i) * ldc + col] = a[i];
      }
    }
  }
}
#undef RD_A8
#undef RD_B4
#undef STAGE_A
#undef STAGE_B
#undef STAGE_ALL
#undef MFMA_Q

// ---------------------------------------------------------------- moe reduce (4 partials)
__global__ __launch_bounds__(256) void moe_reduce(
    const float* __restrict__ part, const float* __restrict__ gate,
    const float* __restrict__ b2, float* __restrict__ moe)
{
  const int row = blockIdx.x;
  const int c = threadIdx.x * 4;
  const size_t o = (size_t)row * D_ + c;
  float4 s = *(const float4*)(part + o);
  #pragma unroll
  for (int zz = 1; zz < 4; ++zz) {
    const float4 p = *(const float4*)(part + (size_t)zz * M_ * D_ + o);
    s.x += p.x; s.y += p.y; s.z += p.z; s.w += p.w;
  }
  #pragma unroll
  for (int e = 0; e < 8; ++e) {
    const float g = gate[(size_t)row * 8 + e];
    const float4 bv = *(const float4*)(b2 + (size_t)e * D_ + c);
    s.x += g * bv.x; s.y += g * bv.y; s.z += g * bv.z; s.w += g * bv.w;
  }
  *(float4*)(moe + o) = s;
}

// ---------------------------------------------------------------- attention
// LDS trimmed to exactly 40960 B (kbuf 16K + vbuf 16K + plds 8K) -> 4
// blocks/CU (was 41472 -> 3). smbuf (256 B) aliases the first 64 B of each
// wave's plds slice: it is written+consumed BEFORE the P-write each
// iteration, and P is fully consumed (PV) before the next rescale/epilogue.
__global__ __launch_bounds__(256, 4) void attn2_kernel(
    const u16* __restrict__ qkv, const float* __restrict__ mask,
    u16* __restrict__ ctx)
{
  __shared__ u16 kbuf[2][KVB * 64];
  __shared__ u16 vbuf[2][KVB * 64];
  __shared__ __align__(16) u16 plds[4][16 * 64];

  const int tid = threadIdx.x, w = tid >> 6, l = tid & 63;
  const int l15 = l & 15, l4 = l >> 4;
  float* smbuf = (float*)&plds[w][0];   // 16 f32, aliases plds[w][0..31]

  // XCD swizzle: nwg = 32*16*2 = 1024
  unsigned wg = blockIdx.x + 32u * (blockIdx.y + 16u * blockIdx.z);
  wg = (wg & 7u) * 128u + (wg >> 3);
  const int qt = (int)(wg & 31u) * 64;
  const unsigned r1 = wg >> 5;
  const int h = (int)(r1 & 15u), b = (int)(r1 >> 4);

  const int qrow = qt + w * 16 + l15;
  const size_t grow = (size_t)b * S_ + qrow;
  bf16x8 qf[2];
  qf[0] = *(const bf16x8*)(qkv + grow * 3072 + h * 64 + l4 * 8);
  qf[1] = *(const bf16x8*)(qkv + grow * 3072 + h * 64 + 32 + l4 * 8);

  const float* maskr = mask + (size_t)b * S_ * S_ + (size_t)qrow * S_;

  f32x4 cacc[4] = {};
  float mrun = -3.0e38f, lrun = 0.0f;

  auto stage = [&](int bf, int kc) {
    #pragma unroll
    for (int ii = 0; ii < 2; ++ii) {
      const int idx = ii * 256 + (w << 6) + l;
      {
        const int key = idx >> 3, pos = idx & 7;
        GLD_LDS16(qkv + ((size_t)b * S_ + kc + key) * 3072 + 1024 + h * 64 + ((pos ^ (key & 7)) << 3),
                  &kbuf[bf][(ii * 256 + (w << 6)) * 8]);
      }
      {
        const int hd = idx & 1, kr = (idx >> 1) & 3, db = (idx >> 3) & 3, kb = idx >> 5;
        GLD_LDS16(qkv + ((size_t)b * S_ + kc + (kb << 2) + kr) * 3072 + 2048 + h * 64 + (db << 4) + (hd << 3),
                  &vbuf[bf][(ii * 256 + (w << 6)) * 8]);
      }
    }
  };

  stage(0, 0);
  __syncthreads();
  int buf = 0;

  for (int kc = 0; kc < S_; kc += KVB) {
    if (kc + KVB < S_) stage(buf ^ 1, kc + KVB);

    f32x4 sacc[4];
    #pragma unroll
    for (int t = 0; t < 4; ++t) sacc[t] = f32x4{0.f, 0.f, 0.f, 0.f};
    #pragma unroll
    for (int t = 0; t < 4; ++t) {
      const int key = 16 * t + l15;
      #pragma unroll
      for (int s = 0; s < 2; ++s) {
        const bf16x8 kf = *(const bf16x8*)&kbuf[buf][key * 64 + ((((s << 2) + l4) ^ (key & 7)) << 3)];
        sacc[t] = __builtin_amdgcn_mfma_f32_16x16x32_bf16(kf, qf[s], sacc[t], 0, 0, 0);
      }
    }

    float sv[4][4]; float pmax = -3.0e38f;
    #pragma unroll
    for (int t = 0; t < 4; ++t) {
      const float4 mk = *(const float4*)(maskr + kc + 16 * t + (l4 << 2));
      sv[t][0] = sacc[t][0] * 0.125f + mk.x;
      sv[t][1] = sacc[t][1] * 0.125f + mk.y;
      sv[t][2] = sacc[t][2] * 0.125f + mk.z;
      sv[t][3] = sacc[t][3] * 0.125f + mk.w;
      pmax = fmaxf(pmax, fmaxf(fmaxf(sv[t][0], sv[t][1]), fmaxf(sv[t][2], sv[t][3])));
    }
    pmax = fmaxf(pmax, __shfl_xor(pmax, 16, 64));
    pmax = fmaxf(pmax, __shfl_xor(pmax, 32, 64));

    if (kc == 0) {
      mrun = pmax;
    } else if (!__all(pmax <= mrun + 2.0f)) {
      const float mn = fmaxf(mrun, pmax);
      const float f = __expf(mrun - mn);
      if (l4 == 0) smbuf[l15] = f;
      float fr[4];
      #pragma unroll
      for (int i = 0; i < 4; ++i) fr[i] = smbuf[(l4 << 2) + i];
      #pragma unroll
      for (int db = 0; db < 4; ++db)
        #pragma unroll
        for (int i = 0; i < 4; ++i) cacc[db][i] *= fr[i];
      lrun *= f;
      mrun = mn;
    }

    float p[4][4]; float lsum = 0.0f;
    #pragma unroll
    for (int t = 0; t < 4; ++t)
      #pragma unroll
      for (int i = 0; i < 4; ++i) { p[t][i] = __expf(sv[t][i] - mrun); lsum += p[t][i]; }
    lsum += __shfl_xor(lsum, 16, 64);
    lsum += __shfl_xor(lsum, 32, 64);
    lrun += lsum;

    #pragma unroll
    for (int t = 0; t < 4; ++t) {
      unsigned pa_, pc_;
      asm("v_cvt_pk_bf16_f32 %0, %1, %2" : "=v"(pa_) : "v"(p[t][0]), "v"(p[t][1]));
      asm("v_cvt_pk_bf16_f32 %0, %1, %2" : "=v"(pc_) : "v"(p[t][2]), "v"(p[t][3]));
      const int byte = l15 * 128 + ((((t << 1) + (l4 >> 1)) ^ (l15 & 7)) << 4) + ((l4 & 1) << 3);
      *(u32x2*)((char*)&plds[w][0] + byte) = (u32x2){pa_, pc_};
    }

    const unsigned vb_off = (unsigned)(uintptr_t)(__attribute__((address_space(3))) void*)&vbuf[buf][0];
    #pragma unroll
    for (int ks = 0; ks < 2; ++ks) {
      const bf16x8 pa = *(const bf16x8*)((char*)&plds[w][0] +
                          l15 * 128 + ((((ks << 2) + l4) ^ (l15 & 7)) << 4));
      u32x2 tv[4][2];
      #pragma unroll
      for (int db = 0; db < 4; ++db) {
        const unsigned va = vb_off + (unsigned)(((ks << 5) + 7 * l4 + db) << 7);
        asm volatile("ds_read_b64_tr_b16 %0, %2\n\t"
                     "ds_read_b64_tr_b16 %1, %2 offset:512"
                     : "=v"(tv[db][0]), "=v"(tv[db][1]) : "v"(va));
      }
      asm volatile("s_waitcnt lgkmcnt(0)" ::: "memory");
      __builtin_amdgcn_sched_barrier(0);
      #pragma unroll
      for (int db = 0; db < 4; ++db) {
        union { unsigned u[4]; bf16x8 v; } vb_;
        vb_.u[0] = tv[db][0].x; vb_.u[1] = tv[db][0].y;
        vb_.u[2] = tv[db][1].x; vb_.u[3] = tv[db][1].y;
        cacc[db] = __builtin_amdgcn_mfma_f32_16x16x32_bf16(pa, vb_.v, cacc[db], 0, 0, 0);
      }
    }
    __syncthreads();
    buf ^= 1;
  }

  if (l4 == 0) smbuf[l15] = 1.0f / lrun;
  float rl[4];
  #pragma unroll
  for (int i = 0; i < 4; ++i) rl[i] = smbuf[(l4 << 2) + i];
  #pragma unroll
  for (int db = 0; db < 4; ++db)
    #pragma unroll
    for (int i = 0; i < 4; ++i) {
      const size_t row = (size_t)b * S_ + qt + w * 16 + (l4 << 2) + i;
      ctx[row * 1024 + h * 64 + (db << 4) + l15] = f2bf(cacc[db][i] * rl[i]);
    }
}

// ---------------------------------------------------------------- layernorm
__global__ __launch_bounds__(256) void ln_kernel(
    const float* __restrict__ x, const float* __restrict__ resid,
    const float* __restrict__ gg, const float* __restrict__ bb,
    float* __restrict__ outf, u16* __restrict__ outb)
{
  const int row = blockIdx.x, t = threadIdx.x;
  const size_t off = (size_t)row * D_ + t * 4;
  const float4 a = *(const float4*)(x + off);
  const float4 r = *(const float4*)(resid + off);
  const float v0 = a.x + r.x, v1 = a.y + r.y, v2 = a.z + r.z, v3 = a.w + r.w;
  float s = v0 + v1 + v2 + v3;
  float s2 = v0*v0 + v1*v1 + v2*v2 + v3*v3;
  #pragma unroll
  for (int d = 1; d < 64; d <<= 1) {
    s += __shfl_xor(s, d, 64);
    s2 += __shfl_xor(s2, d, 64);
  }
  __shared__ float red[8];
  const int w = t >> 6, l = t & 63;
  if (l == 0) { red[w] = s; red[4 + w] = s2; }
  __syncthreads();
  s = red[0] + red[1] + red[2] + red[3];
  s2 = red[4] + red[5] + red[6] + red[7];
  const float mu = s * (1.0f / D_);
  const float rs = rsqrtf(s2 * (1.0f / D_) - mu * mu + 1e-6f);
  const float4 gv = *(const float4*)(gg + t * 4);
  const float4 bv = *(const float4*)(bb + t * 4);
  const float o0 = (v0 - mu) * rs * gv.x + bv.x;
  const float o1 = (v1 - mu) * rs * gv.y + bv.y;
  const float o2 = (v2 - mu) * rs * gv.z + bv.z;
  const float o3 = (v3 - mu) * rs * gv.w + bv.w;
  float4 o; o.x = o0; o.y = o1; o.z = o2; o.w = o3;
  *(float4*)(outf + off) = o;
  if (outb) {
    u16x4 ob = { f2bf(o0), f2bf(o1), f2bf(o2), f2bf(o3) };
    *(u16x4*)(outb + off) = ob;
  }
}

// ---------------------------------------------------------------- gate
__global__ __launch_bounds__(256) void gate_kernel(
    const float* __restrict__ inter, const float* __restrict__ gw,
    const float* __restrict__ gb, float* __restrict__ gout)
{
  const int w = threadIdx.x >> 6, l = threadIdx.x & 63;
  const int row = blockIdx.x * 4 + w;
  float acc[8] = {};
  const float* xr = inter + (size_t)row * D_;
  #pragma unroll 4
  for (int c = 0; c < 16; ++c) {
    const int kk = c * 64 + l;
    const float xv = xr[kk];
    const float4 g0 = *(const float4*)(gw + kk * 8);
    const float4 g1 = *(const float4*)(gw + kk * 8 + 4);
    acc[0] += xv * g0.x; acc[1] += xv * g0.y; acc[2] += xv * g0.z; acc[3] += xv * g0.w;
    acc[4] += xv * g1.x; acc[5] += xv * g1.y; acc[6] += xv * g1.z; acc[7] += xv * g1.w;
  }
  #pragma unroll
  for (int e = 0; e < 8; ++e)
    #pragma unroll
    for (int d = 1; d < 64; d <<= 1) acc[e] += __shfl_xor(acc[e], d, 64);
  float mx = -1e30f;
  #pragma unroll
  for (int e = 0; e < 8; ++e) { acc[e] += gb[e]; mx = fmaxf(mx, acc[e]); }
  float sum = 0.0f;
  #pragma unroll
  for (int e = 0; e < 8; ++e) { acc[e] = __expf(acc[e] - mx); sum += acc[e]; }
  const float inv = 1.0f / sum;
  if (l == 0) {
    #pragma unroll
    for (int e = 0; e < 8; ++e) gout[(size_t)row * 8 + e] = acc[e] * inv;
  }
}

// ---------------------------------------------------------------- launch
extern "C" void kernel_launch(void* const* d_in, const int* in_sizes, int n_in,
                              void* d_out, int out_size, void* d_ws, size_t ws_size,
                              hipStream_t stream) {
  const float* hidden = (const float*)d_in[0];
  const float* mask   = (const float*)d_in[1];
  const float* wq = (const float*)d_in[2];
  const float* bq = (const float*)d_in[3];
  const float* wk = (const float*)d_in[4];
  const float* bk = (const float*)d_in[5];
  const float* wv = (const float*)d_in[6];
  const float* bv = (const float*)d_in[7];
  const float* wo = (const float*)d_in[8];
  const float* bo = (const float*)d_in[9];
  const float* ln1g = (const float*)d_in[10];
  const float* ln1b = (const float*)d_in[11];
  const float* gw = (const float*)d_in[12];
  const float* gb = (const float*)d_in[13];
  const float* w1 = (const float*)d_in[14];
  const float* b1 = (const float*)d_in[15];
  const float* w2 = (const float*)d_in[16];
  const float* b2 = (const float*)d_in[17];
  const float* ln2g = (const float*)d_in[18];
  const float* ln2b = (const float*)d_in[19];

  float* out = (float*)d_out;
  float* gate_out = out + (size_t)M_ * D_;

  char* ws = (char*)d_ws;
  size_t off = 0;
  auto alloc = [&](size_t bytes) -> void* {
    void* p = ws + off;
    off += (bytes + 255) & ~(size_t)255;
    return p;
  };
  // persistent across phases
  float* inter = (float*)alloc((size_t)M_ * D_ * 4);
  u16* interb  = (u16*)alloc((size_t)M_ * D_ * 2);
  float* moe   = (float*)alloc((size_t)M_ * D_ * 4);
  const size_t mark = off;
  // attn-phase region
  u16* xb      = (u16*)alloc((size_t)M_ * D_ * 2);
  u16* wqkvt   = (u16*)alloc((size_t)3 * D_ * D_ * 2);
  float* bqkv  = (float*)alloc((size_t)3 * D_ * 4);
  u16* qkvb    = (u16*)alloc((size_t)M_ * 3 * D_ * 2);
  u16* wot     = (u16*)alloc((size_t)D_ * D_ * 2);
  u16* ctxb    = (u16*)alloc((size_t)M_ * D_ * 2);
  float* tmp   = (float*)alloc((size_t)M_ * D_ * 4);
  const size_t attn_end = off;
  // moe-phase plan A (aliases attn region).
  // part[4][M][D] f32 (64 MiB) ALIASES w1t (64 MiB): w1t dead once GG done.
  off = mark;
  u16* w1t   = (u16*)alloc((size_t)E_ * D_ * F_ * 2);           // [E][F][D]
  u16* w2t2  = (u16*)alloc((size_t)E_ * D_ * F_ * 2);           // [D][E*F]
  u16* hb    = (u16*)alloc((size_t)M_ * E_ * F_ * 2);           // [M][E*F]
  float* part = (float*)w1t;                                    // [4][M][D] alias
  const size_t planA_end = off;
  // moe-phase fallback
  off = mark;
  u16* w1tf = (u16*)alloc((size_t)D_ * F_ * 2);
  u16* w2tf = (u16*)alloc((size_t)D_ * F_ * 2);
  u16* hbf  = (u16*)alloc((size_t)M_ * F_ * 2);
  const bool planA = (planA_end <= ws_size) && (attn_end <= ws_size);

  const dim3 tb(32, 8);

  cvt_kernel<<<M_ * D_ / 1024, 256, 0, stream>>>(hidden, xb);
  transpose_cvt<<<dim3(D_/32, D_/32, 1), tb, 0, stream>>>(wq, wqkvt, D_, D_, D_, 0, 0);
  transpose_cvt<<<dim3(D_/32, D_/32, 1), tb, 0, stream>>>(wk, wqkvt + (size_t)D_*D_, D_, D_, D_, 0, 0);
  transpose_cvt<<<dim3(D_/32, D_/32, 1), tb, 0, stream>>>(wv, wqkvt + (size_t)2*D_*D_, D_, D_, D_, 0, 0);
  transpose_cvt<<<dim3(D_/32, D_/32, 1), tb, 0, stream>>>(wo, wot, D_, D_, D_, 0, 0);
  hipMemcpyAsync(bqkv,        bq, D_ * 4, hipMemcpyDeviceToDevice, stream);
  hipMemcpyAsync(bqkv + D_,   bk, D_ * 4, hipMemcpyDeviceToDevice, stream);
  hipMemcpyAsync(bqkv + 2*D_, bv, D_ * 4, hipMemcpyDeviceToDevice, stream);

  hipFuncSetAttribute((const void*)gemm256<EPI_BF16>, hipFuncAttributeMaxDynamicSharedMemorySize, 131072);
  hipFuncSetAttribute((const void*)gemm256<EPI_GG>,   hipFuncAttributeMaxDynamicSharedMemorySize, 131072);
  hipFuncSetAttribute((const void*)gemm256<EPI_PART>, hipFuncAttributeMaxDynamicSharedMemorySize, 131072);

  gemm256<EPI_BF16><<<dim3(3*D_/256, M_/256, 1), 512, 131072, stream>>>(
      xb, wqkvt, D_, D_, D_, 0, 0, 0, 0, bqkv, qkvb, 3*D_, nullptr);

  attn2_kernel<<<dim3(S_/64, H_, B_), 256, 0, stream>>>(qkvb, mask, ctxb);

  gemm_bf16<EPI_F32,false><<<dim3(D_/BM, M_/BM), 256, 0, stream>>>(ctxb, wot, D_, bo, tmp, D_, nullptr);

  ln_kernel<<<M_, 256, 0, stream>>>(tmp, hidden, ln1g, ln1b, inter, interb);
  gate_kernel<<<M_/4, 256, 0, stream>>>(inter, gw, gb, gate_out);

  if (planA) {
    transpose_cvt<<<dim3(F_/32, D_/32, E_), tb, 0, stream>>>(w1, w1t, D_, F_, D_, (long)D_*F_, (long)F_*D_);
    transpose_cvt<<<dim3(D_/32, F_/32, E_), tb, 0, stream>>>(w2, w2t2, F_, D_, E_*F_, (long)F_*D_, (long)F_);
    // GEMM1 (batched experts): hb[r][e*F+f] = gate_e(r)*gelu(interb@w1_e + b1_e)
    gemm256<EPI_GG><<<dim3(F_/256, M_/256, E_), 512, 131072, stream>>>(
        interb, w1t, D_, D_, D_, 0, (long)D_*F_, (long)F_, F_, b1, hb, E_*F_, gate_out);
    // GEMM2 split-K x4 over fused K = E*F = 32768 (part aliases dead w1t)
    gemm256<EPI_PART><<<dim3(D_/256, M_/256, 4), 512, 131072, stream>>>(
        hb, w2t2, 8192, E_*F_, E_*F_, 8192, 8192, (long)M_*D_, 0, nullptr, part, D_, nullptr);
    moe_reduce<<<M_, 256, 0, stream>>>(part, gate_out, b2, moe);
  } else {
    for (int e = 0; e < E_; ++e) {
      transpose_cvt<<<dim3(F_/32, D_/32, 1), tb, 0, stream>>>(w1 + (size_t)e*D_*F_, w1tf, D_, F_, D_, 0, 0);
      transpose_cvt<<<dim3(D_/32, F_/32, 1), tb, 0, stream>>>(w2 + (size_t)e*F_*D_, w2tf, F_, D_, F_, 0, 0);
      gemm_bf16<EPI_GELU,false><<<dim3(F_/BM, M_/BM), 256, 0, stream>>>(interb, w1tf, D_, b1 + (size_t)e*F_, hbf, F_, nullptr);
      if (e == 0)
        gemm_bf16<EPI_MOE,true ><<<dim3(D_/BM, M_/BM), 256, 0, stream>>>(hbf, w2tf, F_, b2 + (size_t)e*D_, moe, D_, gate_out + e);
      else
        gemm_bf16<EPI_MOE,false><<<dim3(D_/BM, M_/BM), 256, 0, stream>>>(hbf, w2tf, F_, b2 + (size_t)e*D_, moe, D_, gate_out + e);
    }
  }

  ln_kernel<<<M_, 256, 0, stream>>>(moe, inter, ln2g, ln2b, out, nullptr);
}